// Round 1
// baseline (4626.477 us; speedup 1.0000x reference)
//
#include <hip/hip_runtime.h>

#define N_NODES 100000
#define N_EDGES 1600000
#define N_GRAPHS 1024
#define HID 64
#define MLP_HID 128

// ---------------------------------------------------------------------------
// Kernel 1: atom embedding (sum of 9 table rows) + pooled[0] atomics
// thread t: node n = t/16, float4-chunk c = t%16
// ---------------------------------------------------------------------------
__global__ __launch_bounds__(256) void atom_embed_kernel(
    const int* __restrict__ x, const float* __restrict__ atom_emb,
    const int* __restrict__ batch, float* __restrict__ h, float* __restrict__ out)
{
    int t = blockIdx.x * 256 + threadIdx.x;
    if (t >= N_NODES * 16) return;
    int n = t >> 4;
    int c = (t & 15) << 2;
    float4 acc = make_float4(0.f, 0.f, 0.f, 0.f);
#pragma unroll
    for (int f = 0; f < 9; ++f) {
        int idx = x[n * 9 + f];
        const float4 v = *reinterpret_cast<const float4*>(atom_emb + ((f * 119 + idx) * HID + c));
        acc.x += v.x; acc.y += v.y; acc.z += v.z; acc.w += v.w;
    }
    *reinterpret_cast<float4*>(h + n * HID + c) = acc;
    int g = batch[n];
    float* o = out + g * 256 + c;   // pooled[0] occupies cols 0..63
    atomicAdd(o + 0, acc.x);
    atomicAdd(o + 1, acc.y);
    atomicAdd(o + 2, acc.z);
    atomicAdd(o + 3, acc.w);
}

// ---------------------------------------------------------------------------
// Kernel 2: per-edge message + scatter-add
// thread t: edge e = t/16, float4-chunk c = t%16
// msg = relu(h[src] + sum_f edge_emb[f][attr[f]]);  atomicAdd into agg[dst]
// ---------------------------------------------------------------------------
__global__ __launch_bounds__(256) void edge_kernel(
    const int* __restrict__ ei, const int* __restrict__ ea,
    const float* __restrict__ eemb, const float* __restrict__ h,
    float* __restrict__ agg)
{
    int t = blockIdx.x * 256 + threadIdx.x;   // max 25.6M < 2^31
    if (t >= N_EDGES * 16) return;
    int e = t >> 4;
    int c = (t & 15) << 2;
    int src = ei[e];
    int dst = ei[N_EDGES + e];
    int a0 = ea[e * 3 + 0];
    int a1 = ea[e * 3 + 1];
    int a2 = ea[e * 3 + 2];
    const float4 v0 = *reinterpret_cast<const float4*>(eemb + ((0 * 22 + a0) * HID + c));
    const float4 v1 = *reinterpret_cast<const float4*>(eemb + ((1 * 22 + a1) * HID + c));
    const float4 v2 = *reinterpret_cast<const float4*>(eemb + ((2 * 22 + a2) * HID + c));
    const float4 hs = *reinterpret_cast<const float4*>(h + src * HID + c);
    float4 m;
    m.x = fmaxf(hs.x + v0.x + v1.x + v2.x, 0.f);
    m.y = fmaxf(hs.y + v0.y + v1.y + v2.y, 0.f);
    m.z = fmaxf(hs.z + v0.z + v1.z + v2.z, 0.f);
    m.w = fmaxf(hs.w + v0.w + v1.w + v2.w, 0.f);
    float* o = agg + dst * HID + c;
    atomicAdd(o + 0, m.x);
    atomicAdd(o + 1, m.y);
    atomicAdd(o + 2, m.z);
    atomicAdd(o + 3, m.w);
}

// ---------------------------------------------------------------------------
// Kernel 3: node update + MLP (lin1 -> BN -> relu -> lin2 -> relu)
//           + write new h + pooled atomics.  GEMM-tile style: 64 nodes/block,
//           z^T and u^T staged in LDS (padded), weights via wave-uniform
//           scalar loads.  Also zeroes agg for the next layer.
// ---------------------------------------------------------------------------
__global__ __launch_bounds__(256) void node_mlp_kernel(
    float* __restrict__ h, float* __restrict__ agg,
    const float* __restrict__ w1, const float* __restrict__ b1,
    const float* __restrict__ bn_g, const float* __restrict__ bn_b,
    const float* __restrict__ bn_m, const float* __restrict__ bn_v,
    const float* __restrict__ w2, const float* __restrict__ b2,
    const float* __restrict__ eps_p, const int* __restrict__ batch,
    float* __restrict__ out, int out_col)
{
    __shared__ float zs[HID][65];       // z^T : [k][node]   (reused as h^T tile)
    __shared__ float us[MLP_HID][65];   // u^T : [k][node]

    const int tid = threadIdx.x;
    const int lane = tid & 63;
    const int base = blockIdx.x * 64;
    const float ep1 = 1.0f + eps_p[0];

    // ---- stage z = relu((1+eps)*h + agg); zero agg for next layer ----
    for (int i = tid; i < 64 * HID; i += 256) {
        int k = i & 63;
        int n = i >> 6;
        int gn = base + n;
        float z = 0.f;
        if (gn < N_NODES) {
            float hv = h[gn * HID + k];
            float av = agg[gn * HID + k];
            agg[gn * HID + k] = 0.f;
            z = fmaxf(ep1 * hv + av, 0.f);
        }
        zs[k][n] = z;
    }
    __syncthreads();

    const int wv = __builtin_amdgcn_readfirstlane(tid >> 6);  // wave id, scalar

    // ---- lin1 + BN + relu: wave wv computes outputs [wv*32, wv*32+32) ----
    {
        const int o0 = wv * 32;
        float acc[32];
#pragma unroll
        for (int oo = 0; oo < 32; ++oo) acc[oo] = 0.f;
        for (int k = 0; k < HID; ++k) {
            float zk = zs[k][lane];
#pragma unroll
            for (int oo = 0; oo < 32; ++oo)
                acc[oo] = fmaf(w1[(o0 + oo) * HID + k], zk, acc[oo]);
        }
#pragma unroll
        for (int oo = 0; oo < 32; ++oo) {
            int o = o0 + oo;
            float z1 = acc[oo] + b1[o];
            float s = rsqrtf(bn_v[o] + 1e-5f) * bn_g[o];
            float u = fmaxf((z1 - bn_m[o]) * s + bn_b[o], 0.f);
            us[o][lane] = u;
        }
    }
    __syncthreads();

    // ---- lin2 + relu: wave wv computes outputs [wv*16, wv*16+16) ----
    {
        const int o0 = wv * 16;
        float acc[16];
#pragma unroll
        for (int oo = 0; oo < 16; ++oo) acc[oo] = 0.f;
        for (int k = 0; k < MLP_HID; ++k) {
            float uk = us[k][lane];
#pragma unroll
            for (int oo = 0; oo < 16; ++oo)
                acc[oo] = fmaf(w2[(o0 + oo) * MLP_HID + k], uk, acc[oo]);
        }
#pragma unroll
        for (int oo = 0; oo < 16; ++oo) {
            int o = o0 + oo;
            zs[o][lane] = fmaxf(acc[oo] + b2[o], 0.f);   // h^T tile
        }
    }
    __syncthreads();

    // ---- coalesced write-back of h + pooled atomics ----
    for (int i = tid; i < 64 * HID; i += 256) {
        int k = i & 63;
        int n = i >> 6;
        int gn = base + n;
        if (gn < N_NODES) {
            float hv = zs[k][n];
            h[gn * HID + k] = hv;
            atomicAdd(&out[batch[gn] * 256 + out_col + k], hv);
        }
    }
}

// ---------------------------------------------------------------------------
extern "C" void kernel_launch(void* const* d_in, const int* in_sizes, int n_in,
                              void* d_out, int out_size, void* d_ws, size_t ws_size,
                              hipStream_t stream)
{
    const int*   x        = (const int*)d_in[0];
    const int*   ei       = (const int*)d_in[1];
    const int*   ea       = (const int*)d_in[2];
    const int*   batch    = (const int*)d_in[3];
    const float* atom_emb = (const float*)d_in[4];
    const float* edge_emb = (const float*)d_in[5];
    const float* w1       = (const float*)d_in[6];
    const float* b1       = (const float*)d_in[7];
    const float* bn_g     = (const float*)d_in[8];
    const float* bn_b     = (const float*)d_in[9];
    const float* bn_m     = (const float*)d_in[10];
    const float* bn_v     = (const float*)d_in[11];
    const float* w2       = (const float*)d_in[12];
    const float* b2       = (const float*)d_in[13];
    const float* eps      = (const float*)d_in[14];

    float* out = (float*)d_out;
    float* h   = (float*)d_ws;
    float* agg = h + (size_t)N_NODES * HID;

    hipMemsetAsync(out, 0, (size_t)N_GRAPHS * 256 * sizeof(float), stream);
    hipMemsetAsync(agg, 0, (size_t)N_NODES * HID * sizeof(float), stream);

    atom_embed_kernel<<<(N_NODES * 16 + 255) / 256, 256, 0, stream>>>(
        x, atom_emb, batch, h, out);

    for (int l = 0; l < 3; ++l) {
        edge_kernel<<<(N_EDGES * 16) / 256, 256, 0, stream>>>(
            ei, ea, edge_emb + (size_t)l * 3 * 22 * HID, h, agg);
        node_mlp_kernel<<<(N_NODES + 63) / 64, 256, 0, stream>>>(
            h, agg,
            w1 + (size_t)l * MLP_HID * HID, b1 + (size_t)l * MLP_HID,
            bn_g + (size_t)l * MLP_HID, bn_b + (size_t)l * MLP_HID,
            bn_m + (size_t)l * MLP_HID, bn_v + (size_t)l * MLP_HID,
            w2 + (size_t)l * HID * MLP_HID, b2 + (size_t)l * HID,
            eps + l, batch, out, (l + 1) * HID);
    }
}

// Round 2
// 1177.701 us; speedup vs baseline: 3.9284x; 3.9284x over previous
//
#include <hip/hip_runtime.h>

#define N_NODES 100000
#define N_EDGES 1600000
#define N_GRAPHS 1024
#define HID 64
#define MLP_HID 128
#define N_COMBO 264   // 22*6*2 edge-attr combinations

// ---------------------------------------------------------------------------
// Kernel 1: atom embedding (sum of 9 table rows) + pooled[0] atomics
// ---------------------------------------------------------------------------
__global__ __launch_bounds__(256) void atom_embed_kernel(
    const int* __restrict__ x, const float* __restrict__ atom_emb,
    const int* __restrict__ batch, float* __restrict__ h, float* __restrict__ out)
{
    int t = blockIdx.x * 256 + threadIdx.x;
    if (t >= N_NODES * 16) return;
    int n = t >> 4;
    int c = (t & 15) << 2;
    float4 acc = make_float4(0.f, 0.f, 0.f, 0.f);
#pragma unroll
    for (int f = 0; f < 9; ++f) {
        int idx = x[n * 9 + f];
        const float4 v = *reinterpret_cast<const float4*>(atom_emb + ((f * 119 + idx) * HID + c));
        acc.x += v.x; acc.y += v.y; acc.z += v.z; acc.w += v.w;
    }
    *reinterpret_cast<float4*>(h + n * HID + c) = acc;
    int g = batch[n];
    float* o = out + g * 256 + c;   // pooled[0] occupies cols 0..63
    atomicAdd(o + 0, acc.x);
    atomicAdd(o + 1, acc.y);
    atomicAdd(o + 2, acc.z);
    atomicAdd(o + 3, acc.w);
}

// ---------------------------------------------------------------------------
// CSR build: histogram -> scan (3 kernels) -> scatter (packed src|combo)
// ---------------------------------------------------------------------------
__global__ __launch_bounds__(256) void hist_kernel(
    const int* __restrict__ ei, int* __restrict__ cnt)
{
    int e = blockIdx.x * 256 + threadIdx.x;
    if (e < N_EDGES) atomicAdd(&cnt[ei[N_EDGES + e]], 1);
}

__global__ __launch_bounds__(256) void scan1_kernel(
    const int* __restrict__ cnt, int* __restrict__ bsum)
{
    __shared__ int wsum[4];
    int i = blockIdx.x * 256 + threadIdx.x;
    int v = (i < N_NODES) ? cnt[i] : 0;
#pragma unroll
    for (int s = 32; s > 0; s >>= 1) v += __shfl_down(v, s, 64);
    if ((threadIdx.x & 63) == 0) wsum[threadIdx.x >> 6] = v;
    __syncthreads();
    if (threadIdx.x == 0) bsum[blockIdx.x] = wsum[0] + wsum[1] + wsum[2] + wsum[3];
}

__global__ __launch_bounds__(512) void scan2_kernel(
    const int* __restrict__ bsum, int* __restrict__ bpre, int nblk)
{
    __shared__ int buf[512];
    int t = threadIdx.x;
    if (t < nblk) buf[t] = bsum[t];
    __syncthreads();
    if (t == 0) {
        int run = 0;
        for (int i = 0; i < nblk; ++i) { int c = buf[i]; buf[i] = run; run += c; }
    }
    __syncthreads();
    if (t < nblk) bpre[t] = buf[t];
}

__global__ __launch_bounds__(256) void scan3_kernel(
    const int* __restrict__ cnt, const int* __restrict__ bpre, int* __restrict__ off)
{
    __shared__ int buf[256];
    int tid = threadIdx.x;
    int i = blockIdx.x * 256 + tid;
    int v = (i < N_NODES) ? cnt[i] : 0;
    buf[tid] = v;
    __syncthreads();
    for (int s = 1; s < 256; s <<= 1) {
        int t = 0;
        if (tid >= s) t = buf[tid - s];
        __syncthreads();
        if (tid >= s) buf[tid] += t;
        __syncthreads();
    }
    if (i < N_NODES) off[i] = bpre[blockIdx.x] + buf[tid] - v;  // exclusive
}

__global__ __launch_bounds__(256) void scatter_kernel(
    const int* __restrict__ ei, const int* __restrict__ ea,
    int* __restrict__ off, int* __restrict__ csr_e)
{
    int e = blockIdx.x * 256 + threadIdx.x;
    if (e >= N_EDGES) return;
    int src = ei[e];
    int dst = ei[N_EDGES + e];
    int a0 = ea[e * 3 + 0];
    int a1 = ea[e * 3 + 1];
    int a2 = ea[e * 3 + 2];
    int combo = (a0 * 6 + a1) * 2 + a2;            // < 264, 9 bits
    int pos = atomicAdd(&off[dst], 1);
    csr_e[pos] = src | (combo << 17);              // src < 2^17
}

// ---------------------------------------------------------------------------
// Combined edge-embedding table: comb[l][combo][d] = sum of the 3 rows
// ---------------------------------------------------------------------------
__global__ __launch_bounds__(256) void comb_kernel(
    const float* __restrict__ edge_emb, float* __restrict__ comb)
{
    int t = blockIdx.x * 256 + threadIdx.x;
    if (t >= 3 * N_COMBO * HID) return;
    int d = t & 63;
    int c = (t >> 6) % N_COMBO;
    int l = (t >> 6) / N_COMBO;
    int a0 = c / 12, r = c % 12, a1 = r >> 1, a2 = r & 1;
    const float* base = edge_emb + (size_t)l * 3 * 22 * HID;
    comb[t] = base[(0 * 22 + a0) * HID + d]
            + base[(1 * 22 + a1) * HID + d]
            + base[(2 * 22 + a2) * HID + d];
}

// ---------------------------------------------------------------------------
// Gather kernel: one wave per node, lane = feature.
// z[n] = relu((1+eps)*h[n] + sum_{e in in(n)} relu(h[src(e)] + comb[combo(e)]))
// off holds post-scatter cursors = end of each node's segment; beg = end-cnt.
// ---------------------------------------------------------------------------
__global__ __launch_bounds__(256) void gather_kernel(
    const int* __restrict__ cnt, const int* __restrict__ off,
    const int* __restrict__ csr_e, const float* __restrict__ h,
    const float* __restrict__ comb_l, const float* __restrict__ eps_p,
    float* __restrict__ zbuf)
{
    int n = blockIdx.x * 4 + (threadIdx.x >> 6);
    int lane = threadIdx.x & 63;
    if (n >= N_NODES) return;
    int end = off[n];
    int deg = cnt[n];
    int beg = end - deg;
    float acc = 0.f;
    for (int i = beg; i < end; ++i) {
        int pk = csr_e[i];
        int src = pk & 0x1FFFF;
        int cb = pk >> 17;
        float hv = h[src * HID + lane];
        float ev = comb_l[cb * HID + lane];
        acc += fmaxf(hv + ev, 0.f);
    }
    float ep1 = 1.0f + eps_p[0];
    zbuf[n * HID + lane] = fmaxf(ep1 * h[n * HID + lane] + acc, 0.f);
}

// ---------------------------------------------------------------------------
// Node MLP: lin1 -> BN -> relu -> lin2 -> relu, write new h + pooled atomics
// ---------------------------------------------------------------------------
__global__ __launch_bounds__(256) void node_mlp_kernel(
    const float* __restrict__ zbuf, float* __restrict__ h,
    const float* __restrict__ w1, const float* __restrict__ b1,
    const float* __restrict__ bn_g, const float* __restrict__ bn_b,
    const float* __restrict__ bn_m, const float* __restrict__ bn_v,
    const float* __restrict__ w2, const float* __restrict__ b2,
    const int* __restrict__ batch, float* __restrict__ out, int out_col)
{
    __shared__ float zs[HID][65];       // z^T : [k][node]   (reused as h^T tile)
    __shared__ float us[MLP_HID][65];   // u^T : [k][node]

    const int tid = threadIdx.x;
    const int lane = tid & 63;
    const int base = blockIdx.x * 64;

    for (int i = tid; i < 64 * HID; i += 256) {
        int k = i & 63;
        int n = i >> 6;
        int gn = base + n;
        zs[k][n] = (gn < N_NODES) ? zbuf[gn * HID + k] : 0.f;
    }
    __syncthreads();

    const int wv = __builtin_amdgcn_readfirstlane(tid >> 6);  // wave id, scalar

    // ---- lin1 + BN + relu: wave wv computes outputs [wv*32, wv*32+32) ----
    {
        const int o0 = wv * 32;
        float acc[32];
#pragma unroll
        for (int oo = 0; oo < 32; ++oo) acc[oo] = 0.f;
        for (int k = 0; k < HID; ++k) {
            float zk = zs[k][lane];
#pragma unroll
            for (int oo = 0; oo < 32; ++oo)
                acc[oo] = fmaf(w1[(o0 + oo) * HID + k], zk, acc[oo]);
        }
#pragma unroll
        for (int oo = 0; oo < 32; ++oo) {
            int o = o0 + oo;
            float z1 = acc[oo] + b1[o];
            float s = rsqrtf(bn_v[o] + 1e-5f) * bn_g[o];
            float u = fmaxf((z1 - bn_m[o]) * s + bn_b[o], 0.f);
            us[o][lane] = u;
        }
    }
    __syncthreads();

    // ---- lin2 + relu: wave wv computes outputs [wv*16, wv*16+16) ----
    {
        const int o0 = wv * 16;
        float acc[16];
#pragma unroll
        for (int oo = 0; oo < 16; ++oo) acc[oo] = 0.f;
        for (int k = 0; k < MLP_HID; ++k) {
            float uk = us[k][lane];
#pragma unroll
            for (int oo = 0; oo < 16; ++oo)
                acc[oo] = fmaf(w2[(o0 + oo) * MLP_HID + k], uk, acc[oo]);
        }
#pragma unroll
        for (int oo = 0; oo < 16; ++oo) {
            int o = o0 + oo;
            zs[o][lane] = fmaxf(acc[oo] + b2[o], 0.f);   // h^T tile
        }
    }
    __syncthreads();

    for (int i = tid; i < 64 * HID; i += 256) {
        int k = i & 63;
        int n = i >> 6;
        int gn = base + n;
        if (gn < N_NODES) {
            float hv = zs[k][n];
            h[gn * HID + k] = hv;
            atomicAdd(&out[batch[gn] * 256 + out_col + k], hv);
        }
    }
}

// ---------------------------------------------------------------------------
extern "C" void kernel_launch(void* const* d_in, const int* in_sizes, int n_in,
                              void* d_out, int out_size, void* d_ws, size_t ws_size,
                              hipStream_t stream)
{
    const int*   x        = (const int*)d_in[0];
    const int*   ei       = (const int*)d_in[1];
    const int*   ea       = (const int*)d_in[2];
    const int*   batch    = (const int*)d_in[3];
    const float* atom_emb = (const float*)d_in[4];
    const float* edge_emb = (const float*)d_in[5];
    const float* w1       = (const float*)d_in[6];
    const float* b1       = (const float*)d_in[7];
    const float* bn_g     = (const float*)d_in[8];
    const float* bn_b     = (const float*)d_in[9];
    const float* bn_m     = (const float*)d_in[10];
    const float* bn_v     = (const float*)d_in[11];
    const float* w2       = (const float*)d_in[12];
    const float* b2       = (const float*)d_in[13];
    const float* eps      = (const float*)d_in[14];

    float* out = (float*)d_out;

    // workspace layout
    char* ws = (char*)d_ws;
    float* h     = (float*)ws;                     ws += (size_t)N_NODES * HID * 4;   // 25.6 MB
    float* zbuf  = (float*)ws;                     ws += (size_t)N_NODES * HID * 4;   // 25.6 MB
    float* comb  = (float*)ws;                     ws += (size_t)3 * N_COMBO * HID * 4; // 203 KB
    int*   cnt   = (int*)ws;                       ws += (size_t)N_NODES * 4;
    int*   off   = (int*)ws;                       ws += (size_t)N_NODES * 4;
    int*   bsum  = (int*)ws;                       ws += 512 * 4;
    int*   bpre  = (int*)ws;                       ws += 512 * 4;
    int*   csr_e = (int*)ws;                       ws += (size_t)N_EDGES * 4;         // 6.4 MB

    const int nblk = (N_NODES + 255) / 256;        // 391

    hipMemsetAsync(out, 0, (size_t)N_GRAPHS * 256 * sizeof(float), stream);
    hipMemsetAsync(cnt, 0, (size_t)N_NODES * sizeof(int), stream);

    atom_embed_kernel<<<(N_NODES * 16 + 255) / 256, 256, 0, stream>>>(
        x, atom_emb, batch, h, out);

    hist_kernel<<<(N_EDGES + 255) / 256, 256, 0, stream>>>(ei, cnt);
    scan1_kernel<<<nblk, 256, 0, stream>>>(cnt, bsum);
    scan2_kernel<<<1, 512, 0, stream>>>(bsum, bpre, nblk);
    scan3_kernel<<<nblk, 256, 0, stream>>>(cnt, bpre, off);
    scatter_kernel<<<(N_EDGES + 255) / 256, 256, 0, stream>>>(ei, ea, off, csr_e);
    comb_kernel<<<(3 * N_COMBO * HID + 255) / 256, 256, 0, stream>>>(edge_emb, comb);

    for (int l = 0; l < 3; ++l) {
        gather_kernel<<<(N_NODES + 3) / 4, 256, 0, stream>>>(
            cnt, off, csr_e, h, comb + (size_t)l * N_COMBO * HID, eps + l, zbuf);
        node_mlp_kernel<<<(N_NODES + 63) / 64, 256, 0, stream>>>(
            zbuf, h,
            w1 + (size_t)l * MLP_HID * HID, b1 + (size_t)l * MLP_HID,
            bn_g + (size_t)l * MLP_HID, bn_b + (size_t)l * MLP_HID,
            bn_m + (size_t)l * MLP_HID, bn_v + (size_t)l * MLP_HID,
            w2 + (size_t)l * HID * MLP_HID, b2 + (size_t)l * HID,
            batch, out, (l + 1) * HID);
    }
}

// Round 3
// 800.380 us; speedup vs baseline: 5.7803x; 1.4714x over previous
//
#include <hip/hip_runtime.h>

#define N_NODES 100000
#define N_EDGES 1600000
#define N_GRAPHS 1024
#define HID 64
#define MLP_HID 128
#define N_COMBO 264   // 22*6*2 edge-attr combinations

// ---------------------------------------------------------------------------
// Kernel 1: atom embedding (sum of 9 table rows) -> h   (no atomics)
// ---------------------------------------------------------------------------
__global__ __launch_bounds__(256) void atom_embed_kernel(
    const int* __restrict__ x, const float* __restrict__ atom_emb,
    float* __restrict__ h)
{
    int t = blockIdx.x * 256 + threadIdx.x;
    if (t >= N_NODES * 16) return;
    int n = t >> 4;
    int c = (t & 15) << 2;
    float4 acc = make_float4(0.f, 0.f, 0.f, 0.f);
#pragma unroll
    for (int f = 0; f < 9; ++f) {
        int idx = x[n * 9 + f];
        const float4 v = *reinterpret_cast<const float4*>(atom_emb + ((f * 119 + idx) * HID + c));
        acc.x += v.x; acc.y += v.y; acc.z += v.z; acc.w += v.w;
    }
    *reinterpret_cast<float4*>(h + n * HID + c) = acc;
}

// ---------------------------------------------------------------------------
// Segmented pool: block = 64 nodes; thread = (feature, quarter); batch sorted
// -> run-length accumulate, one atomic per (feature, graph-run).
// ---------------------------------------------------------------------------
__global__ __launch_bounds__(256) void pool_kernel(
    const float* __restrict__ h, const int* __restrict__ batch,
    float* __restrict__ out, int out_col)
{
    int base = blockIdx.x * 64;
    int f = threadIdx.x & 63;
    int q = threadIdx.x >> 6;
    float run = 0.f;
    int cg = -1;
    for (int n = q * 16; n < q * 16 + 16; ++n) {
        int gn = base + n;
        if (gn >= N_NODES) break;
        int g = batch[gn];                       // wave-uniform -> broadcast
        if (g != cg) {
            if (cg >= 0) atomicAdd(&out[cg * 256 + out_col + f], run);
            run = 0.f; cg = g;
        }
        run += h[gn * HID + f];                  // coalesced across wave
    }
    if (cg >= 0) atomicAdd(&out[cg * 256 + out_col + f], run);
}

// ---------------------------------------------------------------------------
// CSR build: histogram -> scan (3 kernels) -> scatter (packed src|combo)
// ---------------------------------------------------------------------------
__global__ __launch_bounds__(256) void hist_kernel(
    const int* __restrict__ ei, int* __restrict__ cnt)
{
    int e = blockIdx.x * 256 + threadIdx.x;
    if (e < N_EDGES) atomicAdd(&cnt[ei[N_EDGES + e]], 1);
}

__global__ __launch_bounds__(256) void scan1_kernel(
    const int* __restrict__ cnt, int* __restrict__ bsum)
{
    __shared__ int wsum[4];
    int i = blockIdx.x * 256 + threadIdx.x;
    int v = (i < N_NODES) ? cnt[i] : 0;
#pragma unroll
    for (int s = 32; s > 0; s >>= 1) v += __shfl_down(v, s, 64);
    if ((threadIdx.x & 63) == 0) wsum[threadIdx.x >> 6] = v;
    __syncthreads();
    if (threadIdx.x == 0) bsum[blockIdx.x] = wsum[0] + wsum[1] + wsum[2] + wsum[3];
}

__global__ __launch_bounds__(512) void scan2_kernel(
    const int* __restrict__ bsum, int* __restrict__ bpre, int nblk)
{
    __shared__ int buf[512];
    int t = threadIdx.x;
    if (t < nblk) buf[t] = bsum[t];
    __syncthreads();
    if (t == 0) {
        int run = 0;
        for (int i = 0; i < nblk; ++i) { int c = buf[i]; buf[i] = run; run += c; }
    }
    __syncthreads();
    if (t < nblk) bpre[t] = buf[t];
}

__global__ __launch_bounds__(256) void scan3_kernel(
    const int* __restrict__ cnt, const int* __restrict__ bpre, int* __restrict__ off)
{
    __shared__ int buf[256];
    int tid = threadIdx.x;
    int i = blockIdx.x * 256 + tid;
    int v = (i < N_NODES) ? cnt[i] : 0;
    buf[tid] = v;
    __syncthreads();
    for (int s = 1; s < 256; s <<= 1) {
        int t = 0;
        if (tid >= s) t = buf[tid - s];
        __syncthreads();
        if (tid >= s) buf[tid] += t;
        __syncthreads();
    }
    if (i < N_NODES) off[i] = bpre[blockIdx.x] + buf[tid] - v;  // exclusive
}

__global__ __launch_bounds__(256) void scatter_kernel(
    const int* __restrict__ ei, const int* __restrict__ ea,
    int* __restrict__ off, int* __restrict__ csr_e)
{
    int e = blockIdx.x * 256 + threadIdx.x;
    if (e >= N_EDGES) return;
    int src = ei[e];
    int dst = ei[N_EDGES + e];
    int a0 = ea[e * 3 + 0];
    int a1 = ea[e * 3 + 1];
    int a2 = ea[e * 3 + 2];
    int combo = (a0 * 6 + a1) * 2 + a2;            // < 264, 9 bits
    int pos = atomicAdd(&off[dst], 1);
    csr_e[pos] = src | (combo << 17);              // src < 2^17
}

// ---------------------------------------------------------------------------
// Combined edge-embedding table: comb[l][combo][d] = sum of the 3 rows
// ---------------------------------------------------------------------------
__global__ __launch_bounds__(256) void comb_kernel(
    const float* __restrict__ edge_emb, float* __restrict__ comb)
{
    int t = blockIdx.x * 256 + threadIdx.x;
    if (t >= 3 * N_COMBO * HID) return;
    int d = t & 63;
    int c = (t >> 6) % N_COMBO;
    int l = (t >> 6) / N_COMBO;
    int a0 = c / 12, r = c % 12, a1 = r >> 1, a2 = r & 1;
    const float* base = edge_emb + (size_t)l * 3 * 22 * HID;
    comb[t] = base[(0 * 22 + a0) * HID + d]
            + base[(1 * 22 + a1) * HID + d]
            + base[(2 * 22 + a2) * HID + d];
}

// ---------------------------------------------------------------------------
// Gather: wave per node; 4 x 16-lane groups each own edge slot (i*4+sub),
// lane handles float4 chunk fq. 8 edge rows in flight (2x unroll).
// z[n] = relu((1+eps)*h[n] + sum_e relu(h[src] + comb[combo]))
// ---------------------------------------------------------------------------
__global__ __launch_bounds__(256) void gather_kernel(
    const int* __restrict__ cnt, const int* __restrict__ off,
    const int* __restrict__ csr_e, const float* __restrict__ h,
    const float* __restrict__ comb_l, const float* __restrict__ eps_p,
    float* __restrict__ zbuf)
{
    int n = blockIdx.x * 4 + (threadIdx.x >> 6);
    if (n >= N_NODES) return;
    int lane = threadIdx.x & 63;
    int sub = lane >> 4;          // edge slot 0..3
    int fq = (lane & 15) << 2;    // float4 offset within the 64-float row

    int end = off[n];
    int beg = end - cnt[n];
    float4 acc = make_float4(0.f, 0.f, 0.f, 0.f);

    int i = beg + sub;
    for (; i + 4 < end; i += 8) {
        int pk0 = csr_e[i];
        int pk1 = csr_e[i + 4];
        const float4 h0 = *reinterpret_cast<const float4*>(h + (pk0 & 0x1FFFF) * HID + fq);
        const float4 e0 = *reinterpret_cast<const float4*>(comb_l + (pk0 >> 17) * HID + fq);
        const float4 h1 = *reinterpret_cast<const float4*>(h + (pk1 & 0x1FFFF) * HID + fq);
        const float4 e1 = *reinterpret_cast<const float4*>(comb_l + (pk1 >> 17) * HID + fq);
        acc.x += fmaxf(h0.x + e0.x, 0.f) + fmaxf(h1.x + e1.x, 0.f);
        acc.y += fmaxf(h0.y + e0.y, 0.f) + fmaxf(h1.y + e1.y, 0.f);
        acc.z += fmaxf(h0.z + e0.z, 0.f) + fmaxf(h1.z + e1.z, 0.f);
        acc.w += fmaxf(h0.w + e0.w, 0.f) + fmaxf(h1.w + e1.w, 0.f);
    }
    if (i < end) {
        int pk0 = csr_e[i];
        const float4 h0 = *reinterpret_cast<const float4*>(h + (pk0 & 0x1FFFF) * HID + fq);
        const float4 e0 = *reinterpret_cast<const float4*>(comb_l + (pk0 >> 17) * HID + fq);
        acc.x += fmaxf(h0.x + e0.x, 0.f);
        acc.y += fmaxf(h0.y + e0.y, 0.f);
        acc.z += fmaxf(h0.z + e0.z, 0.f);
        acc.w += fmaxf(h0.w + e0.w, 0.f);
    }

    // reduce across the 4 sub-groups (lane bits 4 and 5)
    acc.x += __shfl_xor(acc.x, 16, 64);
    acc.y += __shfl_xor(acc.y, 16, 64);
    acc.z += __shfl_xor(acc.z, 16, 64);
    acc.w += __shfl_xor(acc.w, 16, 64);
    acc.x += __shfl_xor(acc.x, 32, 64);
    acc.y += __shfl_xor(acc.y, 32, 64);
    acc.z += __shfl_xor(acc.z, 32, 64);
    acc.w += __shfl_xor(acc.w, 32, 64);

    if (sub == 0) {
        const float4 hn = *reinterpret_cast<const float4*>(h + n * HID + fq);
        float ep1 = 1.0f + eps_p[0];
        float4 z;
        z.x = fmaxf(ep1 * hn.x + acc.x, 0.f);
        z.y = fmaxf(ep1 * hn.y + acc.y, 0.f);
        z.z = fmaxf(ep1 * hn.z + acc.z, 0.f);
        z.w = fmaxf(ep1 * hn.w + acc.w, 0.f);
        *reinterpret_cast<float4*>(zbuf + n * HID + fq) = z;
    }
}

// ---------------------------------------------------------------------------
// Node MLP: lin1 -> BN -> relu -> lin2 -> relu; write new h (optional) +
// segmented pooled atomics from the LDS h^T tile.
// ---------------------------------------------------------------------------
__global__ __launch_bounds__(256) void node_mlp_kernel(
    const float* __restrict__ zbuf, float* __restrict__ h,
    const float* __restrict__ w1, const float* __restrict__ b1,
    const float* __restrict__ bn_g, const float* __restrict__ bn_b,
    const float* __restrict__ bn_m, const float* __restrict__ bn_v,
    const float* __restrict__ w2, const float* __restrict__ b2,
    const int* __restrict__ batch, float* __restrict__ out, int out_col,
    int write_h)
{
    __shared__ float zs[HID][65];       // z^T : [k][node]   (reused as h^T tile)
    __shared__ float us[MLP_HID][65];   // u^T : [k][node]
    __shared__ int sbatch[64];

    const int tid = threadIdx.x;
    const int lane = tid & 63;
    const int base = blockIdx.x * 64;

    if (tid < 64) sbatch[tid] = (base + tid < N_NODES) ? batch[base + tid] : -1;
    for (int i = tid; i < 64 * HID; i += 256) {
        int k = i & 63;
        int n = i >> 6;
        int gn = base + n;
        zs[k][n] = (gn < N_NODES) ? zbuf[gn * HID + k] : 0.f;
    }
    __syncthreads();

    const int wv = __builtin_amdgcn_readfirstlane(tid >> 6);  // wave id, scalar

    // ---- lin1 + BN + relu: wave wv computes outputs [wv*32, wv*32+32) ----
    {
        const int o0 = wv * 32;
        float acc[32];
#pragma unroll
        for (int oo = 0; oo < 32; ++oo) acc[oo] = 0.f;
        for (int k = 0; k < HID; ++k) {
            float zk = zs[k][lane];
#pragma unroll
            for (int oo = 0; oo < 32; ++oo)
                acc[oo] = fmaf(w1[(o0 + oo) * HID + k], zk, acc[oo]);
        }
#pragma unroll
        for (int oo = 0; oo < 32; ++oo) {
            int o = o0 + oo;
            float z1 = acc[oo] + b1[o];
            float s = rsqrtf(bn_v[o] + 1e-5f) * bn_g[o];
            float u = fmaxf((z1 - bn_m[o]) * s + bn_b[o], 0.f);
            us[o][lane] = u;
        }
    }
    __syncthreads();

    // ---- lin2 + relu: wave wv computes outputs [wv*16, wv*16+16) ----
    {
        const int o0 = wv * 16;
        float acc[16];
#pragma unroll
        for (int oo = 0; oo < 16; ++oo) acc[oo] = 0.f;
        for (int k = 0; k < MLP_HID; ++k) {
            float uk = us[k][lane];
#pragma unroll
            for (int oo = 0; oo < 16; ++oo)
                acc[oo] = fmaf(w2[(o0 + oo) * MLP_HID + k], uk, acc[oo]);
        }
#pragma unroll
        for (int oo = 0; oo < 16; ++oo) {
            int o = o0 + oo;
            zs[o][lane] = fmaxf(acc[oo] + b2[o], 0.f);   // h^T tile
        }
    }
    __syncthreads();

    // ---- coalesced write-back of h ----
    if (write_h) {
        for (int i = tid; i < 64 * HID; i += 256) {
            int k = i & 63;
            int n = i >> 6;
            int gn = base + n;
            if (gn < N_NODES) h[gn * HID + k] = zs[k][n];
        }
    }

    // ---- segmented pooled atomics: thread = (feature, quarter) ----
    {
        int f = tid & 63;
        int q = tid >> 6;
        float run = 0.f;
        int cg = -1;
        for (int n = q * 16; n < q * 16 + 16; ++n) {
            if (base + n >= N_NODES) break;
            int g = sbatch[n];
            if (g != cg) {
                if (cg >= 0) atomicAdd(&out[cg * 256 + out_col + f], run);
                run = 0.f; cg = g;
            }
            run += zs[f][n];
        }
        if (cg >= 0) atomicAdd(&out[cg * 256 + out_col + f], run);
    }
}

// ---------------------------------------------------------------------------
extern "C" void kernel_launch(void* const* d_in, const int* in_sizes, int n_in,
                              void* d_out, int out_size, void* d_ws, size_t ws_size,
                              hipStream_t stream)
{
    const int*   x        = (const int*)d_in[0];
    const int*   ei       = (const int*)d_in[1];
    const int*   ea       = (const int*)d_in[2];
    const int*   batch    = (const int*)d_in[3];
    const float* atom_emb = (const float*)d_in[4];
    const float* edge_emb = (const float*)d_in[5];
    const float* w1       = (const float*)d_in[6];
    const float* b1       = (const float*)d_in[7];
    const float* bn_g     = (const float*)d_in[8];
    const float* bn_b     = (const float*)d_in[9];
    const float* bn_m     = (const float*)d_in[10];
    const float* bn_v     = (const float*)d_in[11];
    const float* w2       = (const float*)d_in[12];
    const float* b2       = (const float*)d_in[13];
    const float* eps      = (const float*)d_in[14];

    float* out = (float*)d_out;

    // workspace layout
    char* ws = (char*)d_ws;
    float* h     = (float*)ws;                     ws += (size_t)N_NODES * HID * 4;     // 25.6 MB
    float* zbuf  = (float*)ws;                     ws += (size_t)N_NODES * HID * 4;     // 25.6 MB
    float* comb  = (float*)ws;                     ws += (size_t)3 * N_COMBO * HID * 4; // 203 KB
    int*   cnt   = (int*)ws;                       ws += (size_t)N_NODES * 4;
    int*   off   = (int*)ws;                       ws += (size_t)N_NODES * 4;
    int*   bsum  = (int*)ws;                       ws += 512 * 4;
    int*   bpre  = (int*)ws;                       ws += 512 * 4;
    int*   csr_e = (int*)ws;                       ws += (size_t)N_EDGES * 4;           // 6.4 MB

    const int nblk = (N_NODES + 255) / 256;        // 391
    const int nblk64 = (N_NODES + 63) / 64;        // 1563

    hipMemsetAsync(out, 0, (size_t)N_GRAPHS * 256 * sizeof(float), stream);
    hipMemsetAsync(cnt, 0, (size_t)N_NODES * sizeof(int), stream);

    atom_embed_kernel<<<(N_NODES * 16 + 255) / 256, 256, 0, stream>>>(x, atom_emb, h);

    hist_kernel<<<(N_EDGES + 255) / 256, 256, 0, stream>>>(ei, cnt);
    scan1_kernel<<<nblk, 256, 0, stream>>>(cnt, bsum);
    scan2_kernel<<<1, 512, 0, stream>>>(bsum, bpre, nblk);
    scan3_kernel<<<nblk, 256, 0, stream>>>(cnt, bpre, off);
    scatter_kernel<<<(N_EDGES + 255) / 256, 256, 0, stream>>>(ei, ea, off, csr_e);
    comb_kernel<<<(3 * N_COMBO * HID + 255) / 256, 256, 0, stream>>>(edge_emb, comb);

    pool_kernel<<<nblk64, 256, 0, stream>>>(h, batch, out, 0);

    for (int l = 0; l < 3; ++l) {
        gather_kernel<<<(N_NODES + 3) / 4, 256, 0, stream>>>(
            cnt, off, csr_e, h, comb + (size_t)l * N_COMBO * HID, eps + l, zbuf);
        node_mlp_kernel<<<nblk64, 256, 0, stream>>>(
            zbuf, h,
            w1 + (size_t)l * MLP_HID * HID, b1 + (size_t)l * MLP_HID,
            bn_g + (size_t)l * MLP_HID, bn_b + (size_t)l * MLP_HID,
            bn_m + (size_t)l * MLP_HID, bn_v + (size_t)l * MLP_HID,
            w2 + (size_t)l * HID * MLP_HID, b2 + (size_t)l * HID,
            batch, out, (l + 1) * HID, (l < 2) ? 1 : 0);
    }
}

// Round 4
// 477.083 us; speedup vs baseline: 9.6974x; 1.6777x over previous
//
#include <hip/hip_runtime.h>

#define N_NODES 100000
#define N_EDGES 1600000
#define N_GRAPHS 1024
#define HID 64
#define MLP_HID 128
#define N_COMBO 264   // 22*6*2 edge-attr combinations

typedef __attribute__((ext_vector_type(8))) short bf16x8;
typedef __attribute__((ext_vector_type(4))) float f32x4;

static __device__ __forceinline__ float bf2f(unsigned short u) {
    union { unsigned int i; float f; } v; v.i = ((unsigned int)u) << 16; return v.f;
}
static __device__ __forceinline__ unsigned short f2bf(float f) {
    union { float f; unsigned int i; } v; v.f = f;
    unsigned int u = v.i;
    unsigned int r = u + 0x7FFFu + ((u >> 16) & 1u);   // RNE
    return (unsigned short)(r >> 16);
}

// ---------------------------------------------------------------------------
// Kernel 1: atom embedding (sum of 9 f32 table rows) -> h (bf16)
// ---------------------------------------------------------------------------
__global__ __launch_bounds__(256) void atom_embed_kernel(
    const int* __restrict__ x, const float* __restrict__ atom_emb,
    unsigned short* __restrict__ h)
{
    int t = blockIdx.x * 256 + threadIdx.x;
    if (t >= N_NODES * 16) return;
    int n = t >> 4;
    int c = (t & 15) << 2;
    float4 acc = make_float4(0.f, 0.f, 0.f, 0.f);
#pragma unroll
    for (int f = 0; f < 9; ++f) {
        int idx = x[n * 9 + f];
        const float4 v = *reinterpret_cast<const float4*>(atom_emb + ((f * 119 + idx) * HID + c));
        acc.x += v.x; acc.y += v.y; acc.z += v.z; acc.w += v.w;
    }
    ushort4 o4;
    o4.x = f2bf(acc.x); o4.y = f2bf(acc.y); o4.z = f2bf(acc.z); o4.w = f2bf(acc.w);
    *reinterpret_cast<ushort4*>(h + n * HID + c) = o4;
}

// ---------------------------------------------------------------------------
// Segmented pool of bf16 h into out[:, out_col..]; batch sorted.
// ---------------------------------------------------------------------------
__global__ __launch_bounds__(256) void pool_kernel(
    const unsigned short* __restrict__ h, const int* __restrict__ batch,
    float* __restrict__ out, int out_col)
{
    int base = blockIdx.x * 64;
    int f = threadIdx.x & 63;
    int q = threadIdx.x >> 6;
    float run = 0.f;
    int cg = -1;
    for (int n = q * 16; n < q * 16 + 16; ++n) {
        int gn = base + n;
        if (gn >= N_NODES) break;
        int g = batch[gn];
        if (g != cg) {
            if (cg >= 0) atomicAdd(&out[cg * 256 + out_col + f], run);
            run = 0.f; cg = g;
        }
        run += bf2f(h[gn * HID + f]);
    }
    if (cg >= 0) atomicAdd(&out[cg * 256 + out_col + f], run);
}

// ---------------------------------------------------------------------------
// CSR build: histogram -> scan (3 kernels) -> scatter (packed src|combo)
// ---------------------------------------------------------------------------
__global__ __launch_bounds__(256) void hist_kernel(
    const int* __restrict__ ei, int* __restrict__ cnt)
{
    int e = blockIdx.x * 256 + threadIdx.x;
    if (e < N_EDGES) atomicAdd(&cnt[ei[N_EDGES + e]], 1);
}

__global__ __launch_bounds__(256) void scan1_kernel(
    const int* __restrict__ cnt, int* __restrict__ bsum)
{
    __shared__ int wsum[4];
    int i = blockIdx.x * 256 + threadIdx.x;
    int v = (i < N_NODES) ? cnt[i] : 0;
#pragma unroll
    for (int s = 32; s > 0; s >>= 1) v += __shfl_down(v, s, 64);
    if ((threadIdx.x & 63) == 0) wsum[threadIdx.x >> 6] = v;
    __syncthreads();
    if (threadIdx.x == 0) bsum[blockIdx.x] = wsum[0] + wsum[1] + wsum[2] + wsum[3];
}

__global__ __launch_bounds__(512) void scan2_kernel(
    const int* __restrict__ bsum, int* __restrict__ bpre, int nblk)
{
    __shared__ int buf[512];
    int t = threadIdx.x;
    if (t < nblk) buf[t] = bsum[t];
    __syncthreads();
    if (t == 0) {
        int run = 0;
        for (int i = 0; i < nblk; ++i) { int c = buf[i]; buf[i] = run; run += c; }
    }
    __syncthreads();
    if (t < nblk) bpre[t] = buf[t];
}

__global__ __launch_bounds__(256) void scan3_kernel(
    const int* __restrict__ cnt, const int* __restrict__ bpre, int* __restrict__ off)
{
    __shared__ int buf[256];
    int tid = threadIdx.x;
    int i = blockIdx.x * 256 + tid;
    int v = (i < N_NODES) ? cnt[i] : 0;
    buf[tid] = v;
    __syncthreads();
    for (int s = 1; s < 256; s <<= 1) {
        int t = 0;
        if (tid >= s) t = buf[tid - s];
        __syncthreads();
        if (tid >= s) buf[tid] += t;
        __syncthreads();
    }
    if (i < N_NODES) off[i] = bpre[blockIdx.x] + buf[tid] - v;  // exclusive
}

__global__ __launch_bounds__(256) void scatter_kernel(
    const int* __restrict__ ei, const int* __restrict__ ea,
    int* __restrict__ off, int* __restrict__ csr_e)
{
    int e = blockIdx.x * 256 + threadIdx.x;
    if (e >= N_EDGES) return;
    int src = ei[e];
    int dst = ei[N_EDGES + e];
    int a0 = ea[e * 3 + 0];
    int a1 = ea[e * 3 + 1];
    int a2 = ea[e * 3 + 2];
    int combo = (a0 * 6 + a1) * 2 + a2;            // < 264, 9 bits
    int pos = atomicAdd(&off[dst], 1);
    csr_e[pos] = src | (combo << 17);              // src < 2^17
}

// ---------------------------------------------------------------------------
// Combined edge-embedding table (bf16): comb[l][combo][d] = sum of 3 rows
// ---------------------------------------------------------------------------
__global__ __launch_bounds__(256) void comb_kernel(
    const float* __restrict__ edge_emb, unsigned short* __restrict__ comb)
{
    int t = blockIdx.x * 256 + threadIdx.x;
    if (t >= 3 * N_COMBO * HID) return;
    int d = t & 63;
    int c = (t >> 6) % N_COMBO;
    int l = (t >> 6) / N_COMBO;
    int a0 = c / 12, r = c % 12, a1 = r >> 1, a2 = r & 1;
    const float* base = edge_emb + (size_t)l * 3 * 22 * HID;
    comb[t] = f2bf(base[(0 * 22 + a0) * HID + d]
                 + base[(1 * 22 + a1) * HID + d]
                 + base[(2 * 22 + a2) * HID + d]);
}

// ---------------------------------------------------------------------------
// Weight prep: bf16 copies of w1/w2; BN folded to per-output (alpha, beta)
// u = relu(acc*alpha + beta),  alpha = g*rsqrt(v+eps), beta = (b1-m)*alpha + bb
// ---------------------------------------------------------------------------
__global__ __launch_bounds__(256) void wprep_kernel(
    const float* __restrict__ w1, const float* __restrict__ w2,
    const float* __restrict__ b1, const float* __restrict__ bn_g,
    const float* __restrict__ bn_b, const float* __restrict__ bn_m,
    const float* __restrict__ bn_v,
    unsigned short* __restrict__ w1b, unsigned short* __restrict__ w2b,
    float* __restrict__ alpha, float* __restrict__ beta)
{
    int t = blockIdx.x * 256 + threadIdx.x;
    const int NW = 3 * MLP_HID * HID;   // 24576
    if (t < NW) {
        w1b[t] = f2bf(w1[t]);
        w2b[t] = f2bf(w2[t]);
    } else if (t < NW + 3 * MLP_HID) {
        int i = t - NW;
        float a = rsqrtf(bn_v[i] + 1e-5f) * bn_g[i];
        alpha[i] = a;
        beta[i] = (b1[i] - bn_m[i]) * a + bn_b[i];
    }
}

// ---------------------------------------------------------------------------
// Gather: wave per node; 4 x 16-lane groups own edge slot (i*4+sub); lane
// handles 4 features (8B bf16). 4x unroll -> 16 edges in flight per wave.
// z[n] = relu((1+eps)*h[n] + sum_e relu(h[src] + comb[combo]))  (bf16 out)
// ---------------------------------------------------------------------------
__global__ __launch_bounds__(256) void gather_kernel(
    const int* __restrict__ cnt, const int* __restrict__ off,
    const int* __restrict__ csr_e, const unsigned short* __restrict__ h,
    const unsigned short* __restrict__ comb_l, const float* __restrict__ eps_p,
    unsigned short* __restrict__ zbuf)
{
    int n = blockIdx.x * 4 + (threadIdx.x >> 6);
    if (n >= N_NODES) return;
    int lane = threadIdx.x & 63;
    int sub = lane >> 4;          // edge slot 0..3
    int fq = (lane & 15) << 2;    // 4 features

    int end = off[n];
    int beg = end - cnt[n];
    float4 acc = make_float4(0.f, 0.f, 0.f, 0.f);

#define EDGE_ACC(PK)                                                              \
    {                                                                             \
        int pk_ = (PK);                                                           \
        ushort4 hv = *reinterpret_cast<const ushort4*>(h + (pk_ & 0x1FFFF) * HID + fq); \
        ushort4 ev = *reinterpret_cast<const ushort4*>(comb_l + (pk_ >> 17) * HID + fq); \
        acc.x += fmaxf(bf2f(hv.x) + bf2f(ev.x), 0.f);                             \
        acc.y += fmaxf(bf2f(hv.y) + bf2f(ev.y), 0.f);                             \
        acc.z += fmaxf(bf2f(hv.z) + bf2f(ev.z), 0.f);                             \
        acc.w += fmaxf(bf2f(hv.w) + bf2f(ev.w), 0.f);                             \
    }

    int i = beg + sub;
    for (; i + 12 < end; i += 16) {
        int pk0 = csr_e[i];
        int pk1 = csr_e[i + 4];
        int pk2 = csr_e[i + 8];
        int pk3 = csr_e[i + 12];
        EDGE_ACC(pk0); EDGE_ACC(pk1); EDGE_ACC(pk2); EDGE_ACC(pk3);
    }
    for (; i < end; i += 4) {
        EDGE_ACC(csr_e[i]);
    }
#undef EDGE_ACC

    acc.x += __shfl_xor(acc.x, 16, 64);
    acc.y += __shfl_xor(acc.y, 16, 64);
    acc.z += __shfl_xor(acc.z, 16, 64);
    acc.w += __shfl_xor(acc.w, 16, 64);
    acc.x += __shfl_xor(acc.x, 32, 64);
    acc.y += __shfl_xor(acc.y, 32, 64);
    acc.z += __shfl_xor(acc.z, 32, 64);
    acc.w += __shfl_xor(acc.w, 32, 64);

    if (sub == 0) {
        ushort4 hn = *reinterpret_cast<const ushort4*>(h + n * HID + fq);
        float ep1 = 1.0f + eps_p[0];
        ushort4 z;
        z.x = f2bf(fmaxf(ep1 * bf2f(hn.x) + acc.x, 0.f));
        z.y = f2bf(fmaxf(ep1 * bf2f(hn.y) + acc.y, 0.f));
        z.z = f2bf(fmaxf(ep1 * bf2f(hn.z) + acc.z, 0.f));
        z.w = f2bf(fmaxf(ep1 * bf2f(hn.w) + acc.w, 0.f));
        *reinterpret_cast<ushort4*>(zbuf + n * HID + fq) = z;
    }
}

// ---------------------------------------------------------------------------
// MFMA node MLP: 64 nodes/block, 4 waves. lin1(+BN+relu) via 16x16x32 bf16
// MFMA (A = z from global, B = w1 rows), u staged bf16 in XOR-swizzled LDS,
// lin2(+bias+relu) via MFMA, register-level pooled atomics, optional h store.
// ---------------------------------------------------------------------------
__global__ __launch_bounds__(256) void mlp_kernel(
    const unsigned short* __restrict__ zbuf, unsigned short* __restrict__ h,
    const unsigned short* __restrict__ w1b, const unsigned short* __restrict__ w2b,
    const float* __restrict__ alpha, const float* __restrict__ beta,
    const float* __restrict__ b2, const int* __restrict__ batch,
    float* __restrict__ out, int out_col, int write_h)
{
    __shared__ unsigned short us[64 * MLP_HID];   // 16 KB, node-major, swizzled
    __shared__ int sbatch[64];

    const int tid = threadIdx.x;
    const int lane = tid & 63;
    const int w = __builtin_amdgcn_readfirstlane(tid >> 6);
    const int base = blockIdx.x * 64;
    const int r16 = lane & 15;
    const int g4 = lane >> 4;                     // 0..3

    if (tid < 64) sbatch[tid] = (base + tid < N_NODES) ? batch[base + tid] : -1;

    // ---------------- lin1: C[64 nodes][128 out], wave w -> outputs [32w,32w+32)
    f32x4 acc[4][2];
#pragma unroll
    for (int mt = 0; mt < 4; ++mt)
#pragma unroll
        for (int tn = 0; tn < 2; ++tn) acc[mt][tn] = (f32x4){0.f, 0.f, 0.f, 0.f};

    bf16x8 bfrag[2][2];
#pragma unroll
    for (int tn = 0; tn < 2; ++tn)
#pragma unroll
        for (int kt = 0; kt < 2; ++kt) {
            int o = (2 * w + tn) * 16 + r16;
            bfrag[tn][kt] = *reinterpret_cast<const bf16x8*>(w1b + o * HID + kt * 32 + g4 * 8);
        }

#pragma unroll
    for (int mt = 0; mt < 4; ++mt) {
#pragma unroll
        for (int kt = 0; kt < 2; ++kt) {
            bf16x8 af = *reinterpret_cast<const bf16x8*>(
                zbuf + (size_t)(base + mt * 16 + r16) * HID + kt * 32 + g4 * 8);
#pragma unroll
            for (int tn = 0; tn < 2; ++tn)
                acc[mt][tn] = __builtin_amdgcn_mfma_f32_16x16x32_bf16(
                    af, bfrag[tn][kt], acc[mt][tn], 0, 0, 0);
        }
    }

    // BN-fold + relu -> us (bf16, byte ^ ((node&7)<<4) swizzle)
    char* usb = (char*)us;
#pragma unroll
    for (int tn = 0; tn < 2; ++tn) {
        int o = (2 * w + tn) * 16 + r16;
        float al = alpha[o];
        float be = beta[o];
#pragma unroll
        for (int mt = 0; mt < 4; ++mt) {
#pragma unroll
            for (int r = 0; r < 4; ++r) {
                int node = mt * 16 + g4 * 4 + r;
                float u = fmaxf(acc[mt][tn][r] * al + be, 0.f);
                int byte = (node * 256 + o * 2) ^ ((node & 7) << 4);
                *(unsigned short*)(usb + byte) = f2bf(u);
            }
        }
    }
    __syncthreads();

    // ---------------- lin2: C[64 nodes][64 out], wave w -> outputs [16w,16w+16)
    f32x4 acc2[4];
#pragma unroll
    for (int mt = 0; mt < 4; ++mt) acc2[mt] = (f32x4){0.f, 0.f, 0.f, 0.f};

    bf16x8 b2frag[4];
#pragma unroll
    for (int kt = 0; kt < 4; ++kt)
        b2frag[kt] = *reinterpret_cast<const bf16x8*>(
            w2b + (w * 16 + r16) * MLP_HID + kt * 32 + g4 * 8);

#pragma unroll
    for (int mt = 0; mt < 4; ++mt) {
#pragma unroll
        for (int kt = 0; kt < 4; ++kt) {
            int node = mt * 16 + r16;
            int byte = (node * 256 + (kt * 32 + g4 * 8) * 2) ^ ((node & 7) << 4);
            bf16x8 af = *reinterpret_cast<const bf16x8*>(usb + byte);
            acc2[mt] = __builtin_amdgcn_mfma_f32_16x16x32_bf16(
                af, b2frag[kt], acc2[mt], 0, 0, 0);
        }
    }

    // ---------------- epilogue: relu(acc2 + b2), h store, run-merged pooling
    {
        int o = w * 16 + r16;
        float bias = b2[o];
        int gprev = -2;
        float run = 0.f;
#pragma unroll
        for (int mt = 0; mt < 4; ++mt) {
#pragma unroll
            for (int r = 0; r < 4; ++r) {
                int node = mt * 16 + g4 * 4 + r;
                int gn = base + node;
                float v = fmaxf(acc2[mt][r] + bias, 0.f);
                if (write_h && gn < N_NODES) h[(size_t)gn * HID + o] = f2bf(v);
                int gb = sbatch[node];
                if (gb != gprev) {
                    if (gprev >= 0) atomicAdd(&out[gprev * 256 + out_col + o], run);
                    run = 0.f;
                    gprev = gb;
                }
                if (gb >= 0) run += v;
            }
        }
        if (gprev >= 0) atomicAdd(&out[gprev * 256 + out_col + o], run);
    }
}

// ---------------------------------------------------------------------------
extern "C" void kernel_launch(void* const* d_in, const int* in_sizes, int n_in,
                              void* d_out, int out_size, void* d_ws, size_t ws_size,
                              hipStream_t stream)
{
    const int*   x        = (const int*)d_in[0];
    const int*   ei       = (const int*)d_in[1];
    const int*   ea       = (const int*)d_in[2];
    const int*   batch    = (const int*)d_in[3];
    const float* atom_emb = (const float*)d_in[4];
    const float* edge_emb = (const float*)d_in[5];
    const float* w1       = (const float*)d_in[6];
    const float* b1       = (const float*)d_in[7];
    const float* bn_g     = (const float*)d_in[8];
    const float* bn_b     = (const float*)d_in[9];
    const float* bn_m     = (const float*)d_in[10];
    const float* bn_v     = (const float*)d_in[11];
    const float* w2       = (const float*)d_in[12];
    const float* b2       = (const float*)d_in[13];
    const float* eps      = (const float*)d_in[14];

    float* out = (float*)d_out;

    // workspace layout (all 16B-aligned sizes)
    const size_t NODE_PAD = 100064;   // 64-node-block padded row count
    char* ws = (char*)d_ws;
    unsigned short* h     = (unsigned short*)ws; ws += NODE_PAD * HID * 2;           // 12.8 MB
    unsigned short* zbuf  = (unsigned short*)ws; ws += NODE_PAD * HID * 2;           // 12.8 MB
    unsigned short* comb  = (unsigned short*)ws; ws += (size_t)3 * N_COMBO * HID * 2;
    unsigned short* w1b   = (unsigned short*)ws; ws += (size_t)3 * MLP_HID * HID * 2;
    unsigned short* w2b   = (unsigned short*)ws; ws += (size_t)3 * HID * MLP_HID * 2;
    float* alpha          = (float*)ws;          ws += (size_t)3 * MLP_HID * 4;
    float* betab          = (float*)ws;          ws += (size_t)3 * MLP_HID * 4;
    int*   cnt            = (int*)ws;            ws += (size_t)N_NODES * 4;
    int*   off            = (int*)ws;            ws += (size_t)N_NODES * 4;
    int*   bsum           = (int*)ws;            ws += 512 * 4;
    int*   bpre           = (int*)ws;            ws += 512 * 4;
    int*   csr_e          = (int*)ws;            ws += (size_t)N_EDGES * 4;          // 6.4 MB

    const int nblk = (N_NODES + 255) / 256;      // 391
    const int nblk64 = (N_NODES + 63) / 64;      // 1563

    hipMemsetAsync(out, 0, (size_t)N_GRAPHS * 256 * sizeof(float), stream);
    hipMemsetAsync(cnt, 0, (size_t)N_NODES * sizeof(int), stream);

    atom_embed_kernel<<<(N_NODES * 16 + 255) / 256, 256, 0, stream>>>(x, atom_emb, h);

    hist_kernel<<<(N_EDGES + 255) / 256, 256, 0, stream>>>(ei, cnt);
    scan1_kernel<<<nblk, 256, 0, stream>>>(cnt, bsum);
    scan2_kernel<<<1, 512, 0, stream>>>(bsum, bpre, nblk);
    scan3_kernel<<<nblk, 256, 0, stream>>>(cnt, bpre, off);
    scatter_kernel<<<(N_EDGES + 255) / 256, 256, 0, stream>>>(ei, ea, off, csr_e);
    comb_kernel<<<(3 * N_COMBO * HID + 255) / 256, 256, 0, stream>>>(edge_emb, comb);
    wprep_kernel<<<(3 * MLP_HID * HID + 3 * MLP_HID + 255) / 256, 256, 0, stream>>>(
        w1, w2, b1, bn_g, bn_b, bn_m, bn_v, w1b, w2b, alpha, betab);

    pool_kernel<<<nblk64, 256, 0, stream>>>(h, batch, out, 0);

    for (int l = 0; l < 3; ++l) {
        gather_kernel<<<(N_NODES + 3) / 4, 256, 0, stream>>>(
            cnt, off, csr_e, h, comb + (size_t)l * N_COMBO * HID, eps + l, zbuf);
        mlp_kernel<<<nblk64, 256, 0, stream>>>(
            zbuf, h,
            w1b + (size_t)l * MLP_HID * HID, w2b + (size_t)l * HID * MLP_HID,
            alpha + (size_t)l * MLP_HID, betab + (size_t)l * MLP_HID,
            b2 + (size_t)l * HID, batch, out, (l + 1) * HID, (l < 2) ? 1 : 0);
    }
}

// Round 5
// 380.785 us; speedup vs baseline: 12.1498x; 1.2529x over previous
//
#include <hip/hip_runtime.h>

#define N_NODES 100000
#define N_EDGES 1600000
#define N_GRAPHS 1024
#define HID 64
#define MLP_HID 128
#define N_COMBO 264    // 22*6*2 edge-attr combinations
#define NBUCK 98       // ceil(N_NODES / 1024)
#define CHUNK 6144     // edges per bscatter block (48KB LDS staging)

typedef __attribute__((ext_vector_type(8))) short bf16x8;
typedef __attribute__((ext_vector_type(4))) float f32x4;

static __device__ __forceinline__ float bf2f(unsigned short u) {
    union { unsigned int i; float f; } v; v.i = ((unsigned int)u) << 16; return v.f;
}
static __device__ __forceinline__ unsigned short f2bf(float f) {
    union { float f; unsigned int i; } v; v.f = f;
    unsigned int u = v.i;
    unsigned int r = u + 0x7FFFu + ((u >> 16) & 1u);   // RNE
    return (unsigned short)(r >> 16);
}

// ---------------------------------------------------------------------------
// Kernel 1: atom embedding (sum of 9 f32 table rows) -> h (bf16)
// ---------------------------------------------------------------------------
__global__ __launch_bounds__(256) void atom_embed_kernel(
    const int* __restrict__ x, const float* __restrict__ atom_emb,
    unsigned short* __restrict__ h)
{
    int t = blockIdx.x * 256 + threadIdx.x;
    if (t >= N_NODES * 16) return;
    int n = t >> 4;
    int c = (t & 15) << 2;
    float4 acc = make_float4(0.f, 0.f, 0.f, 0.f);
#pragma unroll
    for (int f = 0; f < 9; ++f) {
        int idx = x[n * 9 + f];
        const float4 v = *reinterpret_cast<const float4*>(atom_emb + ((f * 119 + idx) * HID + c));
        acc.x += v.x; acc.y += v.y; acc.z += v.z; acc.w += v.w;
    }
    ushort4 o4;
    o4.x = f2bf(acc.x); o4.y = f2bf(acc.y); o4.z = f2bf(acc.z); o4.w = f2bf(acc.w);
    *reinterpret_cast<ushort4*>(h + n * HID + c) = o4;
}

// ---------------------------------------------------------------------------
// Segmented pool of bf16 h into out[:, out_col..]; batch sorted.
// ---------------------------------------------------------------------------
__global__ __launch_bounds__(256) void pool_kernel(
    const unsigned short* __restrict__ h, const int* __restrict__ batch,
    float* __restrict__ out, int out_col)
{
    int base = blockIdx.x * 64;
    int f = threadIdx.x & 63;
    int q = threadIdx.x >> 6;
    float run = 0.f;
    int cg = -1;
    for (int n = q * 16; n < q * 16 + 16; ++n) {
        int gn = base + n;
        if (gn >= N_NODES) break;
        int g = batch[gn];
        if (g != cg) {
            if (cg >= 0) atomicAdd(&out[cg * 256 + out_col + f], run);
            run = 0.f; cg = g;
        }
        run += bf2f(h[gn * HID + f]);
    }
    if (cg >= 0) atomicAdd(&out[cg * 256 + out_col + f], run);
}

// ---------------------------------------------------------------------------
// Bucketed CSR build.  Bucket b = dst >> 10 (1024 nodes each, NBUCK total).
// bhist: global bucket histogram via per-block LDS histograms.
// ---------------------------------------------------------------------------
__global__ __launch_bounds__(256) void bhist_kernel(
    const int* __restrict__ ei, int* __restrict__ bcnt)
{
    __shared__ int hist[NBUCK];
    int tid = threadIdx.x;
    for (int i = tid; i < NBUCK; i += 256) hist[i] = 0;
    __syncthreads();
    int base = blockIdx.x * 4096;
    int n_here = min(4096, N_EDGES - base);
    for (int i = tid; i < n_here; i += 256)
        atomicAdd(&hist[ei[N_EDGES + base + i] >> 10], 1);
    __syncthreads();
    for (int i = tid; i < NBUCK; i += 256)
        if (hist[i]) atomicAdd(&bcnt[i], hist[i]);
}

// bscan: bbase = exclusive scan of bcnt; bcur = copy; bbase[NBUCK] = N_EDGES
__global__ __launch_bounds__(64) void bscan_kernel(
    const int* __restrict__ bcnt, int* __restrict__ bbase, int* __restrict__ bcur)
{
    if (threadIdx.x == 0) {
        int run = 0;
        for (int b = 0; b < NBUCK; ++b) {
            bbase[b] = run; bcur[b] = run; run += bcnt[b];
        }
        bbase[NBUCK] = run;
    }
}

// bscatter: LDS-staged reorder by bucket, then coalesced run copy-out.
// ebuf entry: {pk = src | combo<<17, dst}
__global__ __launch_bounds__(256) void bscatter_kernel(
    const int* __restrict__ ei, const int* __restrict__ ea,
    int* __restrict__ bcur, uint2* __restrict__ ebuf)
{
    __shared__ uint2 stage[CHUNK];      // 48 KB
    __shared__ int hist[NBUCK];         // counts -> cursors
    __shared__ int lbase[NBUCK];
    __shared__ int shift[NBUCK];

    int tid = threadIdx.x;
    int base = blockIdx.x * CHUNK;
    int n_here = min(CHUNK, N_EDGES - base);

    for (int i = tid; i < NBUCK; i += 256) hist[i] = 0;
    __syncthreads();
    // phase 1: local count
    for (int i = tid; i < n_here; i += 256)
        atomicAdd(&hist[ei[N_EDGES + base + i] >> 10], 1);
    __syncthreads();
    // local exclusive scan (serial, 98 elems)
    if (tid == 0) {
        int run = 0;
        for (int b = 0; b < NBUCK; ++b) { lbase[b] = run; run += hist[b]; }
    }
    __syncthreads();
    // reserve global ranges; reset cursors to lbase
    if (tid < NBUCK) {
        int c = hist[tid];
        if (c > 0) {
            int g = atomicAdd(&bcur[tid], c);
            shift[tid] = g - lbase[tid];
        }
        hist[tid] = lbase[tid];   // reuse as cursor
    }
    __syncthreads();
    // phase 2: stage into LDS grouped by bucket
    for (int i = tid; i < n_here; i += 256) {
        int e = base + i;
        int src = ei[e];
        int dst = ei[N_EDGES + e];
        int combo = (ea[e * 3 + 0] * 6 + ea[e * 3 + 1]) * 2 + ea[e * 3 + 2];
        int pos = atomicAdd(&hist[dst >> 10], 1);
        stage[pos] = make_uint2((unsigned)(src | (combo << 17)), (unsigned)dst);
    }
    __syncthreads();
    // phase 3: coalesced copy-out (runs are contiguous in stage AND in ebuf)
    for (int i = tid; i < n_here; i += 256) {
        uint2 en = stage[i];
        ebuf[shift[en.y >> 10] + i] = en;
    }
}

// csr_build: one block per bucket. Exact per-node CSR within the bucket's
// contiguous csr region; also writes global cnt/off. All random writes are
// confined to this block's 64KB region -> single-L2 resident.
__global__ __launch_bounds__(256) void csr_build_kernel(
    const uint2* __restrict__ ebuf, const int* __restrict__ bbase,
    int* __restrict__ cnt, int* __restrict__ off, int* __restrict__ csr_e)
{
    __shared__ int nh[1024];
    __shared__ int cur[1024];
    __shared__ int part[256];

    int b = blockIdx.x;
    int tid = threadIdx.x;
    int nodeBase = b << 10;
    int limit = min(1024, N_NODES - nodeBase);
    int beg = bbase[b], end = bbase[b + 1];

    for (int i = tid; i < 1024; i += 256) nh[i] = 0;
    __syncthreads();
    for (int i = beg + tid; i < end; i += 256)
        atomicAdd(&nh[ebuf[i].y - nodeBase], 1);
    __syncthreads();

    // exclusive scan of nh[1024]: serial-4 per thread + block scan of partials
    int s0 = nh[tid * 4], s1 = nh[tid * 4 + 1], s2 = nh[tid * 4 + 2], s3 = nh[tid * 4 + 3];
    part[tid] = s0 + s1 + s2 + s3;
    __syncthreads();
    for (int st = 1; st < 256; st <<= 1) {
        int v = 0;
        if (tid >= st) v = part[tid - st];
        __syncthreads();
        if (tid >= st) part[tid] += v;
        __syncthreads();
    }
    int e0 = (tid ? part[tid - 1] : 0);
    int e1 = e0 + s0, e2 = e1 + s1, e3 = e2 + s2;
    cur[tid * 4 + 0] = e0; cur[tid * 4 + 1] = e1;
    cur[tid * 4 + 2] = e2; cur[tid * 4 + 3] = e3;
    // global cnt/off
    int excl[4] = {e0, e1, e2, e3};
    int cval[4] = {s0, s1, s2, s3};
#pragma unroll
    for (int j = 0; j < 4; ++j) {
        int nl = tid * 4 + j;
        if (nl < limit) {
            cnt[nodeBase + nl] = cval[j];
            off[nodeBase + nl] = beg + excl[j];
        }
    }
    __syncthreads();
    // final placement
    for (int i = beg + tid; i < end; i += 256) {
        uint2 en = ebuf[i];
        int pos = atomicAdd(&cur[en.y - nodeBase], 1);
        csr_e[beg + pos] = (int)en.x;
    }
}

// ---------------------------------------------------------------------------
// Combined edge-embedding table (bf16): comb[l][combo][d] = sum of 3 rows
// ---------------------------------------------------------------------------
__global__ __launch_bounds__(256) void comb_kernel(
    const float* __restrict__ edge_emb, unsigned short* __restrict__ comb)
{
    int t = blockIdx.x * 256 + threadIdx.x;
    if (t >= 3 * N_COMBO * HID) return;
    int d = t & 63;
    int c = (t >> 6) % N_COMBO;
    int l = (t >> 6) / N_COMBO;
    int a0 = c / 12, r = c % 12, a1 = r >> 1, a2 = r & 1;
    const float* base = edge_emb + (size_t)l * 3 * 22 * HID;
    comb[t] = f2bf(base[(0 * 22 + a0) * HID + d]
                 + base[(1 * 22 + a1) * HID + d]
                 + base[(2 * 22 + a2) * HID + d]);
}

// ---------------------------------------------------------------------------
// Weight prep: bf16 copies of w1/w2; BN folded to per-output (alpha, beta)
// ---------------------------------------------------------------------------
__global__ __launch_bounds__(256) void wprep_kernel(
    const float* __restrict__ w1, const float* __restrict__ w2,
    const float* __restrict__ b1, const float* __restrict__ bn_g,
    const float* __restrict__ bn_b, const float* __restrict__ bn_m,
    const float* __restrict__ bn_v,
    unsigned short* __restrict__ w1b, unsigned short* __restrict__ w2b,
    float* __restrict__ alpha, float* __restrict__ beta)
{
    int t = blockIdx.x * 256 + threadIdx.x;
    const int NW = 3 * MLP_HID * HID;   // 24576
    if (t < NW) {
        w1b[t] = f2bf(w1[t]);
        w2b[t] = f2bf(w2[t]);
    } else if (t < NW + 3 * MLP_HID) {
        int i = t - NW;
        float a = rsqrtf(bn_v[i] + 1e-5f) * bn_g[i];
        alpha[i] = a;
        beta[i] = (b1[i] - bn_m[i]) * a + bn_b[i];
    }
}

// ---------------------------------------------------------------------------
// Gather: wave per node; 4 x 16-lane groups own edge slot (i*4+sub); lane
// handles 4 features (8B bf16). 16 edges in flight per wave.
// z[n] = relu((1+eps)*h[n] + sum_e relu(h[src] + comb[combo]))  (bf16 out)
// ---------------------------------------------------------------------------
__global__ __launch_bounds__(256) void gather_kernel(
    const int* __restrict__ cnt, const int* __restrict__ off,
    const int* __restrict__ csr_e, const unsigned short* __restrict__ h,
    const unsigned short* __restrict__ comb_l, const float* __restrict__ eps_p,
    unsigned short* __restrict__ zbuf)
{
    int n = blockIdx.x * 4 + (threadIdx.x >> 6);
    if (n >= N_NODES) return;
    int lane = threadIdx.x & 63;
    int sub = lane >> 4;          // edge slot 0..3
    int fq = (lane & 15) << 2;    // 4 features

    int beg = off[n];
    int end = beg + cnt[n];
    float4 acc = make_float4(0.f, 0.f, 0.f, 0.f);

#define EDGE_ACC(PK)                                                              \
    {                                                                             \
        int pk_ = (PK);                                                           \
        ushort4 hv = *reinterpret_cast<const ushort4*>(h + (pk_ & 0x1FFFF) * HID + fq); \
        ushort4 ev = *reinterpret_cast<const ushort4*>(comb_l + (pk_ >> 17) * HID + fq); \
        acc.x += fmaxf(bf2f(hv.x) + bf2f(ev.x), 0.f);                             \
        acc.y += fmaxf(bf2f(hv.y) + bf2f(ev.y), 0.f);                             \
        acc.z += fmaxf(bf2f(hv.z) + bf2f(ev.z), 0.f);                             \
        acc.w += fmaxf(bf2f(hv.w) + bf2f(ev.w), 0.f);                             \
    }

    int i = beg + sub;
    for (; i + 12 < end; i += 16) {
        int pk0 = csr_e[i];
        int pk1 = csr_e[i + 4];
        int pk2 = csr_e[i + 8];
        int pk3 = csr_e[i + 12];
        EDGE_ACC(pk0); EDGE_ACC(pk1); EDGE_ACC(pk2); EDGE_ACC(pk3);
    }
    for (; i < end; i += 4) {
        EDGE_ACC(csr_e[i]);
    }
#undef EDGE_ACC

    acc.x += __shfl_xor(acc.x, 16, 64);
    acc.y += __shfl_xor(acc.y, 16, 64);
    acc.z += __shfl_xor(acc.z, 16, 64);
    acc.w += __shfl_xor(acc.w, 16, 64);
    acc.x += __shfl_xor(acc.x, 32, 64);
    acc.y += __shfl_xor(acc.y, 32, 64);
    acc.z += __shfl_xor(acc.z, 32, 64);
    acc.w += __shfl_xor(acc.w, 32, 64);

    if (sub == 0) {
        ushort4 hn = *reinterpret_cast<const ushort4*>(h + n * HID + fq);
        float ep1 = 1.0f + eps_p[0];
        ushort4 z;
        z.x = f2bf(fmaxf(ep1 * bf2f(hn.x) + acc.x, 0.f));
        z.y = f2bf(fmaxf(ep1 * bf2f(hn.y) + acc.y, 0.f));
        z.z = f2bf(fmaxf(ep1 * bf2f(hn.z) + acc.z, 0.f));
        z.w = f2bf(fmaxf(ep1 * bf2f(hn.w) + acc.w, 0.f));
        *reinterpret_cast<ushort4*>(zbuf + n * HID + fq) = z;
    }
}

// ---------------------------------------------------------------------------
// MFMA node MLP (unchanged from round 3)
// ---------------------------------------------------------------------------
__global__ __launch_bounds__(256) void mlp_kernel(
    const unsigned short* __restrict__ zbuf, unsigned short* __restrict__ h,
    const unsigned short* __restrict__ w1b, const unsigned short* __restrict__ w2b,
    const float* __restrict__ alpha, const float* __restrict__ beta,
    const float* __restrict__ b2, const int* __restrict__ batch,
    float* __restrict__ out, int out_col, int write_h)
{
    __shared__ unsigned short us[64 * MLP_HID];   // 16 KB, node-major, swizzled
    __shared__ int sbatch[64];

    const int tid = threadIdx.x;
    const int lane = tid & 63;
    const int w = __builtin_amdgcn_readfirstlane(tid >> 6);
    const int base = blockIdx.x * 64;
    const int r16 = lane & 15;
    const int g4 = lane >> 4;                     // 0..3

    if (tid < 64) sbatch[tid] = (base + tid < N_NODES) ? batch[base + tid] : -1;

    f32x4 acc[4][2];
#pragma unroll
    for (int mt = 0; mt < 4; ++mt)
#pragma unroll
        for (int tn = 0; tn < 2; ++tn) acc[mt][tn] = (f32x4){0.f, 0.f, 0.f, 0.f};

    bf16x8 bfrag[2][2];
#pragma unroll
    for (int tn = 0; tn < 2; ++tn)
#pragma unroll
        for (int kt = 0; kt < 2; ++kt) {
            int o = (2 * w + tn) * 16 + r16;
            bfrag[tn][kt] = *reinterpret_cast<const bf16x8*>(w1b + o * HID + kt * 32 + g4 * 8);
        }

#pragma unroll
    for (int mt = 0; mt < 4; ++mt) {
#pragma unroll
        for (int kt = 0; kt < 2; ++kt) {
            bf16x8 af = *reinterpret_cast<const bf16x8*>(
                zbuf + (size_t)(base + mt * 16 + r16) * HID + kt * 32 + g4 * 8);
#pragma unroll
            for (int tn = 0; tn < 2; ++tn)
                acc[mt][tn] = __builtin_amdgcn_mfma_f32_16x16x32_bf16(
                    af, bfrag[tn][kt], acc[mt][tn], 0, 0, 0);
        }
    }

    char* usb = (char*)us;
#pragma unroll
    for (int tn = 0; tn < 2; ++tn) {
        int o = (2 * w + tn) * 16 + r16;
        float al = alpha[o];
        float be = beta[o];
#pragma unroll
        for (int mt = 0; mt < 4; ++mt) {
#pragma unroll
            for (int r = 0; r < 4; ++r) {
                int node = mt * 16 + g4 * 4 + r;
                float u = fmaxf(acc[mt][tn][r] * al + be, 0.f);
                int byte = (node * 256 + o * 2) ^ ((node & 7) << 4);
                *(unsigned short*)(usb + byte) = f2bf(u);
            }
        }
    }
    __syncthreads();

    f32x4 acc2[4];
#pragma unroll
    for (int mt = 0; mt < 4; ++mt) acc2[mt] = (f32x4){0.f, 0.f, 0.f, 0.f};

    bf16x8 b2frag[4];
#pragma unroll
    for (int kt = 0; kt < 4; ++kt)
        b2frag[kt] = *reinterpret_cast<const bf16x8*>(
            w2b + (w * 16 + r16) * MLP_HID + kt * 32 + g4 * 8);

#pragma unroll
    for (int mt = 0; mt < 4; ++mt) {
#pragma unroll
        for (int kt = 0; kt < 4; ++kt) {
            int node = mt * 16 + r16;
            int byte = (node * 256 + (kt * 32 + g4 * 8) * 2) ^ ((node & 7) << 4);
            bf16x8 af = *reinterpret_cast<const bf16x8*>(usb + byte);
            acc2[mt] = __builtin_amdgcn_mfma_f32_16x16x32_bf16(
                af, b2frag[kt], acc2[mt], 0, 0, 0);
        }
    }

    {
        int o = w * 16 + r16;
        float bias = b2[o];
        int gprev = -2;
        float run = 0.f;
#pragma unroll
        for (int mt = 0; mt < 4; ++mt) {
#pragma unroll
            for (int r = 0; r < 4; ++r) {
                int node = mt * 16 + g4 * 4 + r;
                int gn = base + node;
                float v = fmaxf(acc2[mt][r] + bias, 0.f);
                if (write_h && gn < N_NODES) h[(size_t)gn * HID + o] = f2bf(v);
                int gb = sbatch[node];
                if (gb != gprev) {
                    if (gprev >= 0) atomicAdd(&out[gprev * 256 + out_col + o], run);
                    run = 0.f;
                    gprev = gb;
                }
                if (gb >= 0) run += v;
            }
        }
        if (gprev >= 0) atomicAdd(&out[gprev * 256 + out_col + o], run);
    }
}

// ---------------------------------------------------------------------------
extern "C" void kernel_launch(void* const* d_in, const int* in_sizes, int n_in,
                              void* d_out, int out_size, void* d_ws, size_t ws_size,
                              hipStream_t stream)
{
    const int*   x        = (const int*)d_in[0];
    const int*   ei       = (const int*)d_in[1];
    const int*   ea       = (const int*)d_in[2];
    const int*   batch    = (const int*)d_in[3];
    const float* atom_emb = (const float*)d_in[4];
    const float* edge_emb = (const float*)d_in[5];
    const float* w1       = (const float*)d_in[6];
    const float* b1       = (const float*)d_in[7];
    const float* bn_g     = (const float*)d_in[8];
    const float* bn_b     = (const float*)d_in[9];
    const float* bn_m     = (const float*)d_in[10];
    const float* bn_v     = (const float*)d_in[11];
    const float* w2       = (const float*)d_in[12];
    const float* b2       = (const float*)d_in[13];
    const float* eps      = (const float*)d_in[14];

    float* out = (float*)d_out;

    // workspace layout (all chunks 16B-aligned)
    const size_t NODE_PAD = 100064;
    char* ws = (char*)d_ws;
    unsigned short* h     = (unsigned short*)ws; ws += NODE_PAD * HID * 2;            // 12.8 MB
    unsigned short* zbuf  = (unsigned short*)ws; ws += NODE_PAD * HID * 2;            // 12.8 MB
    unsigned short* comb  = (unsigned short*)ws; ws += (size_t)3 * N_COMBO * HID * 2;
    unsigned short* w1b   = (unsigned short*)ws; ws += (size_t)3 * MLP_HID * HID * 2;
    unsigned short* w2b   = (unsigned short*)ws; ws += (size_t)3 * HID * MLP_HID * 2;
    float* alpha          = (float*)ws;          ws += (size_t)3 * MLP_HID * 4;
    float* betab          = (float*)ws;          ws += (size_t)3 * MLP_HID * 4;
    int*   cnt            = (int*)ws;            ws += (size_t)N_NODES * 4;
    int*   off            = (int*)ws;            ws += (size_t)N_NODES * 4;
    int*   bcnt           = (int*)ws;            ws += 128 * 4;
    int*   bbase          = (int*)ws;            ws += 128 * 4;
    int*   bcur           = (int*)ws;            ws += 128 * 4;
    uint2* ebuf           = (uint2*)ws;          ws += (size_t)N_EDGES * 8;           // 12.8 MB
    int*   csr_e          = (int*)ws;            ws += (size_t)N_EDGES * 4;           // 6.4 MB

    const int nblk64 = (N_NODES + 63) / 64;      // 1563

    hipMemsetAsync(out, 0, (size_t)N_GRAPHS * 256 * sizeof(float), stream);
    hipMemsetAsync(bcnt, 0, 128 * sizeof(int), stream);

    atom_embed_kernel<<<(N_NODES * 16 + 255) / 256, 256, 0, stream>>>(x, atom_emb, h);

    bhist_kernel<<<(N_EDGES + 4095) / 4096, 256, 0, stream>>>(ei, bcnt);
    bscan_kernel<<<1, 64, 0, stream>>>(bcnt, bbase, bcur);
    bscatter_kernel<<<(N_EDGES + CHUNK - 1) / CHUNK, 256, 0, stream>>>(ei, ea, bcur, ebuf);
    csr_build_kernel<<<NBUCK, 256, 0, stream>>>(ebuf, bbase, cnt, off, csr_e);

    comb_kernel<<<(3 * N_COMBO * HID + 255) / 256, 256, 0, stream>>>(edge_emb, comb);
    wprep_kernel<<<(3 * MLP_HID * HID + 3 * MLP_HID + 255) / 256, 256, 0, stream>>>(
        w1, w2, b1, bn_g, bn_b, bn_m, bn_v, w1b, w2b, alpha, betab);

    pool_kernel<<<nblk64, 256, 0, stream>>>(h, batch, out, 0);

    for (int l = 0; l < 3; ++l) {
        gather_kernel<<<(N_NODES + 3) / 4, 256, 0, stream>>>(
            cnt, off, csr_e, h, comb + (size_t)l * N_COMBO * HID, eps + l, zbuf);
        mlp_kernel<<<nblk64, 256, 0, stream>>>(
            zbuf, h,
            w1b + (size_t)l * MLP_HID * HID, w2b + (size_t)l * HID * MLP_HID,
            alpha + (size_t)l * MLP_HID, betab + (size_t)l * MLP_HID,
            b2 + (size_t)l * HID, batch, out, (l + 1) * HID, (l < 2) ? 1 : 0);
    }
}

// Round 6
// 349.313 us; speedup vs baseline: 13.2445x; 1.0901x over previous
//
#include <hip/hip_runtime.h>

#define N_NODES 100000
#define N_EDGES 1600000
#define N_GRAPHS 1024
#define HID 64
#define MLP_HID 128
#define N_COMBO 264    // 22*6*2 edge-attr combinations
#define NBUCK 98       // ceil(N_NODES / 1024)
#define CHUNK 6144     // edges per bscatter block (48KB LDS staging)

typedef __attribute__((ext_vector_type(8))) short bf16x8;
typedef __attribute__((ext_vector_type(4))) float f32x4;
typedef __attribute__((ext_vector_type(2))) float f32x2;

static __device__ __forceinline__ float bf2f(unsigned short u) {
    union { unsigned int i; float f; } v; v.i = ((unsigned int)u) << 16; return v.f;
}
static __device__ __forceinline__ unsigned short f2bf(float f) {
    union { float f; unsigned int i; } v; v.f = f;
    unsigned int u = v.i;
    unsigned int r = u + 0x7FFFu + ((u >> 16) & 1u);   // RNE
    return (unsigned short)(r >> 16);
}
// expand a packed bf16 pair (u32) to 2 floats (1 VALU op per float)
static __device__ __forceinline__ f32x2 bfpair(unsigned int u) {
    union { unsigned int i; float f; } lo, hi;
    lo.i = u << 16;
    hi.i = u & 0xFFFF0000u;
    f32x2 r; r.x = lo.f; r.y = hi.f; return r;
}
static __device__ __forceinline__ unsigned int pack2bf(float a, float b) {
    return (unsigned int)f2bf(a) | ((unsigned int)f2bf(b) << 16);
}

// ---------------------------------------------------------------------------
// Kernel 1: atom embedding (sum of 9 f32 table rows) -> h (bf16)
// ---------------------------------------------------------------------------
__global__ __launch_bounds__(256) void atom_embed_kernel(
    const int* __restrict__ x, const float* __restrict__ atom_emb,
    unsigned short* __restrict__ h)
{
    int t = blockIdx.x * 256 + threadIdx.x;
    if (t >= N_NODES * 16) return;
    int n = t >> 4;
    int c = (t & 15) << 2;
    float4 acc = make_float4(0.f, 0.f, 0.f, 0.f);
#pragma unroll
    for (int f = 0; f < 9; ++f) {
        int idx = x[n * 9 + f];
        const float4 v = *reinterpret_cast<const float4*>(atom_emb + ((f * 119 + idx) * HID + c));
        acc.x += v.x; acc.y += v.y; acc.z += v.z; acc.w += v.w;
    }
    ushort4 o4;
    o4.x = f2bf(acc.x); o4.y = f2bf(acc.y); o4.z = f2bf(acc.z); o4.w = f2bf(acc.w);
    *reinterpret_cast<ushort4*>(h + n * HID + c) = o4;
}

// ---------------------------------------------------------------------------
// Segmented pool of bf16 h into out[:, out_col..]; batch sorted.
// ---------------------------------------------------------------------------
__global__ __launch_bounds__(256) void pool_kernel(
    const unsigned short* __restrict__ h, const int* __restrict__ batch,
    float* __restrict__ out, int out_col)
{
    int base = blockIdx.x * 64;
    int f = threadIdx.x & 63;
    int q = threadIdx.x >> 6;
    float run = 0.f;
    int cg = -1;
    for (int n = q * 16; n < q * 16 + 16; ++n) {
        int gn = base + n;
        if (gn >= N_NODES) break;
        int g = batch[gn];
        if (g != cg) {
            if (cg >= 0) atomicAdd(&out[cg * 256 + out_col + f], run);
            run = 0.f; cg = g;
        }
        run += bf2f(h[gn * HID + f]);
    }
    if (cg >= 0) atomicAdd(&out[cg * 256 + out_col + f], run);
}

// ---------------------------------------------------------------------------
// Bucketed CSR build.  Bucket b = dst >> 10 (1024 nodes each, NBUCK total).
// ---------------------------------------------------------------------------
__global__ __launch_bounds__(256) void bhist_kernel(
    const int* __restrict__ ei, int* __restrict__ bcnt)
{
    __shared__ int hist[NBUCK];
    int tid = threadIdx.x;
    for (int i = tid; i < NBUCK; i += 256) hist[i] = 0;
    __syncthreads();
    int base = blockIdx.x * 4096;
    int n_here = min(4096, N_EDGES - base);
    for (int i = tid; i < n_here; i += 256)
        atomicAdd(&hist[ei[N_EDGES + base + i] >> 10], 1);
    __syncthreads();
    for (int i = tid; i < NBUCK; i += 256)
        if (hist[i]) atomicAdd(&bcnt[i], hist[i]);
}

__global__ __launch_bounds__(64) void bscan_kernel(
    const int* __restrict__ bcnt, int* __restrict__ bbase, int* __restrict__ bcur)
{
    if (threadIdx.x == 0) {
        int run = 0;
        for (int b = 0; b < NBUCK; ++b) {
            bbase[b] = run; bcur[b] = run; run += bcnt[b];
        }
        bbase[NBUCK] = run;
    }
}

__global__ __launch_bounds__(256) void bscatter_kernel(
    const int* __restrict__ ei, const int* __restrict__ ea,
    int* __restrict__ bcur, uint2* __restrict__ ebuf)
{
    __shared__ uint2 stage[CHUNK];      // 48 KB
    __shared__ int hist[NBUCK];
    __shared__ int lbase[NBUCK];
    __shared__ int shift[NBUCK];

    int tid = threadIdx.x;
    int base = blockIdx.x * CHUNK;
    int n_here = min(CHUNK, N_EDGES - base);

    for (int i = tid; i < NBUCK; i += 256) hist[i] = 0;
    __syncthreads();
    for (int i = tid; i < n_here; i += 256)
        atomicAdd(&hist[ei[N_EDGES + base + i] >> 10], 1);
    __syncthreads();
    if (tid == 0) {
        int run = 0;
        for (int b = 0; b < NBUCK; ++b) { lbase[b] = run; run += hist[b]; }
    }
    __syncthreads();
    if (tid < NBUCK) {
        int c = hist[tid];
        if (c > 0) {
            int g = atomicAdd(&bcur[tid], c);
            shift[tid] = g - lbase[tid];
        }
        hist[tid] = lbase[tid];
    }
    __syncthreads();
    for (int i = tid; i < n_here; i += 256) {
        int e = base + i;
        int src = ei[e];
        int dst = ei[N_EDGES + e];
        int combo = (ea[e * 3 + 0] * 6 + ea[e * 3 + 1]) * 2 + ea[e * 3 + 2];
        int pos = atomicAdd(&hist[dst >> 10], 1);
        stage[pos] = make_uint2((unsigned)(src | (combo << 17)), (unsigned)dst);
    }
    __syncthreads();
    for (int i = tid; i < n_here; i += 256) {
        uint2 en = stage[i];
        ebuf[shift[en.y >> 10] + i] = en;
    }
}

__global__ __launch_bounds__(256) void csr_build_kernel(
    const uint2* __restrict__ ebuf, const int* __restrict__ bbase,
    int* __restrict__ cnt, int* __restrict__ off, int* __restrict__ csr_e)
{
    __shared__ int nh[1024];
    __shared__ int cur[1024];
    __shared__ int part[256];

    int b = blockIdx.x;
    int tid = threadIdx.x;
    int nodeBase = b << 10;
    int limit = min(1024, N_NODES - nodeBase);
    int beg = bbase[b], end = bbase[b + 1];

    for (int i = tid; i < 1024; i += 256) nh[i] = 0;
    __syncthreads();
    for (int i = beg + tid; i < end; i += 256)
        atomicAdd(&nh[ebuf[i].y - nodeBase], 1);
    __syncthreads();

    int s0 = nh[tid * 4], s1 = nh[tid * 4 + 1], s2 = nh[tid * 4 + 2], s3 = nh[tid * 4 + 3];
    part[tid] = s0 + s1 + s2 + s3;
    __syncthreads();
    for (int st = 1; st < 256; st <<= 1) {
        int v = 0;
        if (tid >= st) v = part[tid - st];
        __syncthreads();
        if (tid >= st) part[tid] += v;
        __syncthreads();
    }
    int e0 = (tid ? part[tid - 1] : 0);
    int e1 = e0 + s0, e2 = e1 + s1, e3 = e2 + s2;
    cur[tid * 4 + 0] = e0; cur[tid * 4 + 1] = e1;
    cur[tid * 4 + 2] = e2; cur[tid * 4 + 3] = e3;
    int excl[4] = {e0, e1, e2, e3};
    int cval[4] = {s0, s1, s2, s3};
#pragma unroll
    for (int j = 0; j < 4; ++j) {
        int nl = tid * 4 + j;
        if (nl < limit) {
            cnt[nodeBase + nl] = cval[j];
            off[nodeBase + nl] = beg + excl[j];
        }
    }
    __syncthreads();
    for (int i = beg + tid; i < end; i += 256) {
        uint2 en = ebuf[i];
        int pos = atomicAdd(&cur[en.y - nodeBase], 1);
        csr_e[beg + pos] = (int)en.x;
    }
}

// ---------------------------------------------------------------------------
// Combined edge-embedding table (bf16): comb[l][combo][d] = sum of 3 rows
// ---------------------------------------------------------------------------
__global__ __launch_bounds__(256) void comb_kernel(
    const float* __restrict__ edge_emb, unsigned short* __restrict__ comb)
{
    int t = blockIdx.x * 256 + threadIdx.x;
    if (t >= 3 * N_COMBO * HID) return;
    int d = t & 63;
    int c = (t >> 6) % N_COMBO;
    int l = (t >> 6) / N_COMBO;
    int a0 = c / 12, r = c % 12, a1 = r >> 1, a2 = r & 1;
    const float* base = edge_emb + (size_t)l * 3 * 22 * HID;
    comb[t] = f2bf(base[(0 * 22 + a0) * HID + d]
                 + base[(1 * 22 + a1) * HID + d]
                 + base[(2 * 22 + a2) * HID + d]);
}

// ---------------------------------------------------------------------------
// Weight prep: bf16 copies of w1/w2; BN folded to per-output (alpha, beta)
// ---------------------------------------------------------------------------
__global__ __launch_bounds__(256) void wprep_kernel(
    const float* __restrict__ w1, const float* __restrict__ w2,
    const float* __restrict__ b1, const float* __restrict__ bn_g,
    const float* __restrict__ bn_b, const float* __restrict__ bn_m,
    const float* __restrict__ bn_v,
    unsigned short* __restrict__ w1b, unsigned short* __restrict__ w2b,
    float* __restrict__ alpha, float* __restrict__ beta)
{
    int t = blockIdx.x * 256 + threadIdx.x;
    const int NW = 3 * MLP_HID * HID;   // 24576
    if (t < NW) {
        w1b[t] = f2bf(w1[t]);
        w2b[t] = f2bf(w2[t]);
    } else if (t < NW + 3 * MLP_HID) {
        int i = t - NW;
        float a = rsqrtf(bn_v[i] + 1e-5f) * bn_g[i];
        alpha[i] = a;
        beta[i] = (b1[i] - bn_m[i]) * a + bn_b[i];
    }
}

// ---------------------------------------------------------------------------
// Gather: wave per node; 8 x 8-lane groups own edge slot (i*8+sub); lane
// handles 8 features (16B uint4 loads). Packed f32x2 math (v_pk_*).
// z[n] = relu((1+eps)*h[n] + sum_e relu(h[src] + comb[combo]))  (bf16 out)
// ---------------------------------------------------------------------------
__global__ __launch_bounds__(256) void gather_kernel(
    const int* __restrict__ cnt, const int* __restrict__ off,
    const int* __restrict__ csr_e, const unsigned short* __restrict__ h,
    const unsigned short* __restrict__ comb_l, const float* __restrict__ eps_p,
    unsigned short* __restrict__ zbuf)
{
    int n = blockIdx.x * 4 + (threadIdx.x >> 6);
    if (n >= N_NODES) return;
    int lane = threadIdx.x & 63;
    int sub = lane >> 3;          // edge slot 0..7
    int fo = (lane & 7) << 3;     // 8 features per lane

    int beg = off[n];
    int end = beg + cnt[n];

    const f32x2 zero2 = {0.f, 0.f};
    f32x2 a0 = zero2, a1 = zero2, a2 = zero2, a3 = zero2;

#define EDGE_ACC(PK)                                                               \
    {                                                                              \
        int pk_ = (PK);                                                            \
        uint4 hv = *reinterpret_cast<const uint4*>(h + (pk_ & 0x1FFFF) * HID + fo);\
        uint4 ev = *reinterpret_cast<const uint4*>(comb_l + (pk_ >> 17) * HID + fo);\
        a0 += __builtin_elementwise_max(bfpair(hv.x) + bfpair(ev.x), zero2);       \
        a1 += __builtin_elementwise_max(bfpair(hv.y) + bfpair(ev.y), zero2);       \
        a2 += __builtin_elementwise_max(bfpair(hv.z) + bfpair(ev.z), zero2);       \
        a3 += __builtin_elementwise_max(bfpair(hv.w) + bfpair(ev.w), zero2);       \
    }

    int i = beg + sub;
    for (; i + 8 < end; i += 16) {
        int pk0 = csr_e[i];
        int pk1 = csr_e[i + 8];
        EDGE_ACC(pk0);
        EDGE_ACC(pk1);
    }
    if (i < end) EDGE_ACC(csr_e[i]);
#undef EDGE_ACC

    // reduce across the 8 sub-groups (lane bits 3,4,5)
    float r[8] = {a0.x, a0.y, a1.x, a1.y, a2.x, a2.y, a3.x, a3.y};
#pragma unroll
    for (int j = 0; j < 8; ++j) {
        r[j] += __shfl_xor(r[j], 8, 64);
        r[j] += __shfl_xor(r[j], 16, 64);
        r[j] += __shfl_xor(r[j], 32, 64);
    }

    if (sub == 0) {
        uint4 hn = *reinterpret_cast<const uint4*>(h + n * HID + fo);
        float ep1 = 1.0f + eps_p[0];
        f32x2 ep2 = {ep1, ep1};
        f32x2 z0 = __builtin_elementwise_max(ep2 * bfpair(hn.x) + (f32x2){r[0], r[1]}, zero2);
        f32x2 z1 = __builtin_elementwise_max(ep2 * bfpair(hn.y) + (f32x2){r[2], r[3]}, zero2);
        f32x2 z2 = __builtin_elementwise_max(ep2 * bfpair(hn.z) + (f32x2){r[4], r[5]}, zero2);
        f32x2 z3 = __builtin_elementwise_max(ep2 * bfpair(hn.w) + (f32x2){r[6], r[7]}, zero2);
        uint4 o;
        o.x = pack2bf(z0.x, z0.y);
        o.y = pack2bf(z1.x, z1.y);
        o.z = pack2bf(z2.x, z2.y);
        o.w = pack2bf(z3.x, z3.y);
        *reinterpret_cast<uint4*>(zbuf + n * HID + fo) = o;
    }
}

// ---------------------------------------------------------------------------
// MFMA node MLP (unchanged)
// ---------------------------------------------------------------------------
__global__ __launch_bounds__(256) void mlp_kernel(
    const unsigned short* __restrict__ zbuf, unsigned short* __restrict__ h,
    const unsigned short* __restrict__ w1b, const unsigned short* __restrict__ w2b,
    const float* __restrict__ alpha, const float* __restrict__ beta,
    const float* __restrict__ b2, const int* __restrict__ batch,
    float* __restrict__ out, int out_col, int write_h)
{
    __shared__ unsigned short us[64 * MLP_HID];   // 16 KB, node-major, swizzled
    __shared__ int sbatch[64];

    const int tid = threadIdx.x;
    const int lane = tid & 63;
    const int w = __builtin_amdgcn_readfirstlane(tid >> 6);
    const int base = blockIdx.x * 64;
    const int r16 = lane & 15;
    const int g4 = lane >> 4;                     // 0..3

    if (tid < 64) sbatch[tid] = (base + tid < N_NODES) ? batch[base + tid] : -1;

    f32x4 acc[4][2];
#pragma unroll
    for (int mt = 0; mt < 4; ++mt)
#pragma unroll
        for (int tn = 0; tn < 2; ++tn) acc[mt][tn] = (f32x4){0.f, 0.f, 0.f, 0.f};

    bf16x8 bfrag[2][2];
#pragma unroll
    for (int tn = 0; tn < 2; ++tn)
#pragma unroll
        for (int kt = 0; kt < 2; ++kt) {
            int o = (2 * w + tn) * 16 + r16;
            bfrag[tn][kt] = *reinterpret_cast<const bf16x8*>(w1b + o * HID + kt * 32 + g4 * 8);
        }

#pragma unroll
    for (int mt = 0; mt < 4; ++mt) {
#pragma unroll
        for (int kt = 0; kt < 2; ++kt) {
            bf16x8 af = *reinterpret_cast<const bf16x8*>(
                zbuf + (size_t)(base + mt * 16 + r16) * HID + kt * 32 + g4 * 8);
#pragma unroll
            for (int tn = 0; tn < 2; ++tn)
                acc[mt][tn] = __builtin_amdgcn_mfma_f32_16x16x32_bf16(
                    af, bfrag[tn][kt], acc[mt][tn], 0, 0, 0);
        }
    }

    char* usb = (char*)us;
#pragma unroll
    for (int tn = 0; tn < 2; ++tn) {
        int o = (2 * w + tn) * 16 + r16;
        float al = alpha[o];
        float be = beta[o];
#pragma unroll
        for (int mt = 0; mt < 4; ++mt) {
#pragma unroll
            for (int r = 0; r < 4; ++r) {
                int node = mt * 16 + g4 * 4 + r;
                float u = fmaxf(acc[mt][tn][r] * al + be, 0.f);
                int byte = (node * 256 + o * 2) ^ ((node & 7) << 4);
                *(unsigned short*)(usb + byte) = f2bf(u);
            }
        }
    }
    __syncthreads();

    f32x4 acc2[4];
#pragma unroll
    for (int mt = 0; mt < 4; ++mt) acc2[mt] = (f32x4){0.f, 0.f, 0.f, 0.f};

    bf16x8 b2frag[4];
#pragma unroll
    for (int kt = 0; kt < 4; ++kt)
        b2frag[kt] = *reinterpret_cast<const bf16x8*>(
            w2b + (w * 16 + r16) * MLP_HID + kt * 32 + g4 * 8);

#pragma unroll
    for (int mt = 0; mt < 4; ++mt) {
#pragma unroll
        for (int kt = 0; kt < 4; ++kt) {
            int node = mt * 16 + r16;
            int byte = (node * 256 + (kt * 32 + g4 * 8) * 2) ^ ((node & 7) << 4);
            bf16x8 af = *reinterpret_cast<const bf16x8*>(usb + byte);
            acc2[mt] = __builtin_amdgcn_mfma_f32_16x16x32_bf16(
                af, b2frag[kt], acc2[mt], 0, 0, 0);
        }
    }

    {
        int o = w * 16 + r16;
        float bias = b2[o];
        int gprev = -2;
        float run = 0.f;
#pragma unroll
        for (int mt = 0; mt < 4; ++mt) {
#pragma unroll
            for (int r = 0; r < 4; ++r) {
                int node = mt * 16 + g4 * 4 + r;
                int gn = base + node;
                float v = fmaxf(acc2[mt][r] + bias, 0.f);
                if (write_h && gn < N_NODES) h[(size_t)gn * HID + o] = f2bf(v);
                int gb = sbatch[node];
                if (gb != gprev) {
                    if (gprev >= 0) atomicAdd(&out[gprev * 256 + out_col + o], run);
                    run = 0.f;
                    gprev = gb;
                }
                if (gb >= 0) run += v;
            }
        }
        if (gprev >= 0) atomicAdd(&out[gprev * 256 + out_col + o], run);
    }
}

// ---------------------------------------------------------------------------
extern "C" void kernel_launch(void* const* d_in, const int* in_sizes, int n_in,
                              void* d_out, int out_size, void* d_ws, size_t ws_size,
                              hipStream_t stream)
{
    const int*   x        = (const int*)d_in[0];
    const int*   ei       = (const int*)d_in[1];
    const int*   ea       = (const int*)d_in[2];
    const int*   batch    = (const int*)d_in[3];
    const float* atom_emb = (const float*)d_in[4];
    const float* edge_emb = (const float*)d_in[5];
    const float* w1       = (const float*)d_in[6];
    const float* b1       = (const float*)d_in[7];
    const float* bn_g     = (const float*)d_in[8];
    const float* bn_b     = (const float*)d_in[9];
    const float* bn_m     = (const float*)d_in[10];
    const float* bn_v     = (const float*)d_in[11];
    const float* w2       = (const float*)d_in[12];
    const float* b2       = (const float*)d_in[13];
    const float* eps      = (const float*)d_in[14];

    float* out = (float*)d_out;

    // workspace layout (all chunks 16B-aligned)
    const size_t NODE_PAD = 100064;
    char* ws = (char*)d_ws;
    unsigned short* h     = (unsigned short*)ws; ws += NODE_PAD * HID * 2;            // 12.8 MB
    unsigned short* zbuf  = (unsigned short*)ws; ws += NODE_PAD * HID * 2;            // 12.8 MB
    unsigned short* comb  = (unsigned short*)ws; ws += (size_t)3 * N_COMBO * HID * 2;
    unsigned short* w1b   = (unsigned short*)ws; ws += (size_t)3 * MLP_HID * HID * 2;
    unsigned short* w2b   = (unsigned short*)ws; ws += (size_t)3 * HID * MLP_HID * 2;
    float* alpha          = (float*)ws;          ws += (size_t)3 * MLP_HID * 4;
    float* betab          = (float*)ws;          ws += (size_t)3 * MLP_HID * 4;
    int*   cnt            = (int*)ws;            ws += (size_t)N_NODES * 4;
    int*   off            = (int*)ws;            ws += (size_t)N_NODES * 4;
    int*   bcnt           = (int*)ws;            ws += 128 * 4;
    int*   bbase          = (int*)ws;            ws += 128 * 4;
    int*   bcur           = (int*)ws;            ws += 128 * 4;
    uint2* ebuf           = (uint2*)ws;          ws += (size_t)N_EDGES * 8;           // 12.8 MB
    int*   csr_e          = (int*)ws;            ws += (size_t)N_EDGES * 4;           // 6.4 MB

    const int nblk64 = (N_NODES + 63) / 64;      // 1563

    hipMemsetAsync(out, 0, (size_t)N_GRAPHS * 256 * sizeof(float), stream);
    hipMemsetAsync(bcnt, 0, 128 * sizeof(int), stream);

    atom_embed_kernel<<<(N_NODES * 16 + 255) / 256, 256, 0, stream>>>(x, atom_emb, h);

    bhist_kernel<<<(N_EDGES + 4095) / 4096, 256, 0, stream>>>(ei, bcnt);
    bscan_kernel<<<1, 64, 0, stream>>>(bcnt, bbase, bcur);
    bscatter_kernel<<<(N_EDGES + CHUNK - 1) / CHUNK, 256, 0, stream>>>(ei, ea, bcur, ebuf);
    csr_build_kernel<<<NBUCK, 256, 0, stream>>>(ebuf, bbase, cnt, off, csr_e);

    comb_kernel<<<(3 * N_COMBO * HID + 255) / 256, 256, 0, stream>>>(edge_emb, comb);
    wprep_kernel<<<(3 * MLP_HID * HID + 3 * MLP_HID + 255) / 256, 256, 0, stream>>>(
        w1, w2, b1, bn_g, bn_b, bn_m, bn_v, w1b, w2b, alpha, betab);

    pool_kernel<<<nblk64, 256, 0, stream>>>(h, batch, out, 0);

    for (int l = 0; l < 3; ++l) {
        gather_kernel<<<(N_NODES + 3) / 4, 256, 0, stream>>>(
            cnt, off, csr_e, h, comb + (size_t)l * N_COMBO * HID, eps + l, zbuf);
        mlp_kernel<<<nblk64, 256, 0, stream>>>(
            zbuf, h,
            w1b + (size_t)l * MLP_HID * HID, w2b + (size_t)l * HID * MLP_HID,
            alpha + (size_t)l * MLP_HID, betab + (size_t)l * MLP_HID,
            b2 + (size_t)l * HID, batch, out, (l + 1) * HID, (l < 2) ? 1 : 0);
    }
}

// Round 7
// 339.147 us; speedup vs baseline: 13.6415x; 1.0300x over previous
//
#include <hip/hip_runtime.h>

#define N_NODES 100000
#define N_EDGES 1600000
#define N_GRAPHS 1024
#define HID 64
#define MLP_HID 128
#define N_COMBO 264    // 22*6*2 edge-attr combinations
#define NBUCK 98       // ceil(N_NODES / 1024)
#define CHUNK 6144     // edges per bscatter block (48KB LDS staging)

typedef __attribute__((ext_vector_type(8))) short bf16x8;
typedef __attribute__((ext_vector_type(4))) float f32x4;
typedef __attribute__((ext_vector_type(2))) float f32x2;

static __device__ __forceinline__ float bf2f(unsigned short u) {
    union { unsigned int i; float f; } v; v.i = ((unsigned int)u) << 16; return v.f;
}
static __device__ __forceinline__ unsigned short f2bf(float f) {
    union { float f; unsigned int i; } v; v.f = f;
    unsigned int u = v.i;
    unsigned int r = u + 0x7FFFu + ((u >> 16) & 1u);   // RNE
    return (unsigned short)(r >> 16);
}
// expand a packed bf16 pair (u32) to 2 floats (1 VALU op per float)
static __device__ __forceinline__ f32x2 bfpair(unsigned int u) {
    union { unsigned int i; float f; } lo, hi;
    lo.i = u << 16;
    hi.i = u & 0xFFFF0000u;
    f32x2 r; r.x = lo.f; r.y = hi.f; return r;
}
static __device__ __forceinline__ unsigned int pack2bf(float a, float b) {
    return (unsigned int)f2bf(a) | ((unsigned int)f2bf(b) << 16);
}

// ---------------------------------------------------------------------------
// Kernel 1: atom embedding (sum of 9 f32 table rows) -> h (bf16)
// ---------------------------------------------------------------------------
__global__ __launch_bounds__(256) void atom_embed_kernel(
    const int* __restrict__ x, const float* __restrict__ atom_emb,
    unsigned short* __restrict__ h)
{
    int t = blockIdx.x * 256 + threadIdx.x;
    if (t >= N_NODES * 16) return;
    int n = t >> 4;
    int c = (t & 15) << 2;
    float4 acc = make_float4(0.f, 0.f, 0.f, 0.f);
#pragma unroll
    for (int f = 0; f < 9; ++f) {
        int idx = x[n * 9 + f];
        const float4 v = *reinterpret_cast<const float4*>(atom_emb + ((f * 119 + idx) * HID + c));
        acc.x += v.x; acc.y += v.y; acc.z += v.z; acc.w += v.w;
    }
    ushort4 o4;
    o4.x = f2bf(acc.x); o4.y = f2bf(acc.y); o4.z = f2bf(acc.z); o4.w = f2bf(acc.w);
    *reinterpret_cast<ushort4*>(h + n * HID + c) = o4;
}

// ---------------------------------------------------------------------------
// Segmented pool of bf16 h into out[:, out_col..]; batch sorted.
// ---------------------------------------------------------------------------
__global__ __launch_bounds__(256) void pool_kernel(
    const unsigned short* __restrict__ h, const int* __restrict__ batch,
    float* __restrict__ out, int out_col)
{
    int base = blockIdx.x * 64;
    int f = threadIdx.x & 63;
    int q = threadIdx.x >> 6;
    float run = 0.f;
    int cg = -1;
    for (int n = q * 16; n < q * 16 + 16; ++n) {
        int gn = base + n;
        if (gn >= N_NODES) break;
        int g = batch[gn];
        if (g != cg) {
            if (cg >= 0) atomicAdd(&out[cg * 256 + out_col + f], run);
            run = 0.f; cg = g;
        }
        run += bf2f(h[gn * HID + f]);
    }
    if (cg >= 0) atomicAdd(&out[cg * 256 + out_col + f], run);
}

// ---------------------------------------------------------------------------
// Bucketed CSR build.  Bucket b = dst >> 10 (1024 nodes each, NBUCK total).
// ---------------------------------------------------------------------------
__global__ __launch_bounds__(256) void bhist_kernel(
    const int* __restrict__ ei, int* __restrict__ bcnt)
{
    __shared__ int hist[NBUCK];
    int tid = threadIdx.x;
    for (int i = tid; i < NBUCK; i += 256) hist[i] = 0;
    __syncthreads();
    int base = blockIdx.x * 4096;
    int n_here = min(4096, N_EDGES - base);
    for (int i = tid; i < n_here; i += 256)
        atomicAdd(&hist[ei[N_EDGES + base + i] >> 10], 1);
    __syncthreads();
    for (int i = tid; i < NBUCK; i += 256)
        if (hist[i]) atomicAdd(&bcnt[i], hist[i]);
}

__global__ __launch_bounds__(64) void bscan_kernel(
    const int* __restrict__ bcnt, int* __restrict__ bbase, int* __restrict__ bcur)
{
    if (threadIdx.x == 0) {
        int run = 0;
        for (int b = 0; b < NBUCK; ++b) {
            bbase[b] = run; bcur[b] = run; run += bcnt[b];
        }
        bbase[NBUCK] = run;
    }
}

__global__ __launch_bounds__(256) void bscatter_kernel(
    const int* __restrict__ ei, const int* __restrict__ ea,
    int* __restrict__ bcur, uint2* __restrict__ ebuf)
{
    __shared__ uint2 stage[CHUNK];      // 48 KB
    __shared__ int hist[NBUCK];
    __shared__ int lbase[NBUCK];
    __shared__ int shift[NBUCK];

    int tid = threadIdx.x;
    int base = blockIdx.x * CHUNK;
    int n_here = min(CHUNK, N_EDGES - base);

    for (int i = tid; i < NBUCK; i += 256) hist[i] = 0;
    __syncthreads();
    for (int i = tid; i < n_here; i += 256)
        atomicAdd(&hist[ei[N_EDGES + base + i] >> 10], 1);
    __syncthreads();
    if (tid == 0) {
        int run = 0;
        for (int b = 0; b < NBUCK; ++b) { lbase[b] = run; run += hist[b]; }
    }
    __syncthreads();
    if (tid < NBUCK) {
        int c = hist[tid];
        if (c > 0) {
            int g = atomicAdd(&bcur[tid], c);
            shift[tid] = g - lbase[tid];
        }
        hist[tid] = lbase[tid];
    }
    __syncthreads();
    for (int i = tid; i < n_here; i += 256) {
        int e = base + i;
        int src = ei[e];
        int dst = ei[N_EDGES + e];
        int combo = (ea[e * 3 + 0] * 6 + ea[e * 3 + 1]) * 2 + ea[e * 3 + 2];
        int pos = atomicAdd(&hist[dst >> 10], 1);
        stage[pos] = make_uint2((unsigned)(src | (combo << 17)), (unsigned)dst);
    }
    __syncthreads();
    for (int i = tid; i < n_here; i += 256) {
        uint2 en = stage[i];
        ebuf[shift[en.y >> 10] + i] = en;
    }
}

__global__ __launch_bounds__(256) void csr_build_kernel(
    const uint2* __restrict__ ebuf, const int* __restrict__ bbase,
    int* __restrict__ cnt, int* __restrict__ off, int* __restrict__ csr_e)
{
    __shared__ int nh[1024];
    __shared__ int cur[1024];
    __shared__ int part[256];

    int b = blockIdx.x;
    int tid = threadIdx.x;
    int nodeBase = b << 10;
    int limit = min(1024, N_NODES - nodeBase);
    int beg = bbase[b], end = bbase[b + 1];

    for (int i = tid; i < 1024; i += 256) nh[i] = 0;
    __syncthreads();
    for (int i = beg + tid; i < end; i += 256)
        atomicAdd(&nh[ebuf[i].y - nodeBase], 1);
    __syncthreads();

    int s0 = nh[tid * 4], s1 = nh[tid * 4 + 1], s2 = nh[tid * 4 + 2], s3 = nh[tid * 4 + 3];
    part[tid] = s0 + s1 + s2 + s3;
    __syncthreads();
    for (int st = 1; st < 256; st <<= 1) {
        int v = 0;
        if (tid >= st) v = part[tid - st];
        __syncthreads();
        if (tid >= st) part[tid] += v;
        __syncthreads();
    }
    int e0 = (tid ? part[tid - 1] : 0);
    int e1 = e0 + s0, e2 = e1 + s1, e3 = e2 + s2;
    cur[tid * 4 + 0] = e0; cur[tid * 4 + 1] = e1;
    cur[tid * 4 + 2] = e2; cur[tid * 4 + 3] = e3;
    int excl[4] = {e0, e1, e2, e3};
    int cval[4] = {s0, s1, s2, s3};
#pragma unroll
    for (int j = 0; j < 4; ++j) {
        int nl = tid * 4 + j;
        if (nl < limit) {
            cnt[nodeBase + nl] = cval[j];
            off[nodeBase + nl] = beg + excl[j];
        }
    }
    __syncthreads();
    for (int i = beg + tid; i < end; i += 256) {
        uint2 en = ebuf[i];
        int pos = atomicAdd(&cur[en.y - nodeBase], 1);
        csr_e[beg + pos] = (int)en.x;
    }
}

// ---------------------------------------------------------------------------
// Prep: f32 combined edge table + bf16 weights + folded BN affine. One launch.
// ---------------------------------------------------------------------------
__global__ __launch_bounds__(256) void prep_kernel(
    const float* __restrict__ edge_emb,
    const float* __restrict__ w1, const float* __restrict__ w2,
    const float* __restrict__ b1, const float* __restrict__ bn_g,
    const float* __restrict__ bn_b, const float* __restrict__ bn_m,
    const float* __restrict__ bn_v,
    float* __restrict__ comb,
    unsigned short* __restrict__ w1b, unsigned short* __restrict__ w2b,
    float* __restrict__ alpha, float* __restrict__ beta)
{
    int t = blockIdx.x * 256 + threadIdx.x;
    const int NC = 3 * N_COMBO * HID;   // 50688
    const int NW = 3 * MLP_HID * HID;   // 24576
    if (t < NC) {
        int d = t & 63;
        int c = (t >> 6) % N_COMBO;
        int l = (t >> 6) / N_COMBO;
        int a0 = c / 12, r = c % 12, a1 = r >> 1, a2 = r & 1;
        const float* base = edge_emb + (size_t)l * 3 * 22 * HID;
        comb[t] = base[(0 * 22 + a0) * HID + d]
                + base[(1 * 22 + a1) * HID + d]
                + base[(2 * 22 + a2) * HID + d];
    } else if (t < NC + NW) {
        int i = t - NC;
        w1b[i] = f2bf(w1[i]);
        w2b[i] = f2bf(w2[i]);
    } else if (t < NC + NW + 3 * MLP_HID) {
        int i = t - NC - NW;
        float a = rsqrtf(bn_v[i] + 1e-5f) * bn_g[i];
        alpha[i] = a;
        beta[i] = (b1[i] - bn_m[i]) * a + bn_b[i];
    }
}

// ---------------------------------------------------------------------------
// Gather: wave per node; 8 x 8-lane groups own edge slot (i*8+sub); lane
// handles 8 features. h is bf16 (16B load), comb is f32 (2x16B, L2-hit) ->
// halves the per-feature convert work. Packed f32x2 math (v_pk_*).
// z[n] = relu((1+eps)*h[n] + sum_e relu(h[src] + comb[combo]))  (bf16 out)
// ---------------------------------------------------------------------------
__global__ __launch_bounds__(256) void gather_kernel(
    const int* __restrict__ cnt, const int* __restrict__ off,
    const int* __restrict__ csr_e, const unsigned short* __restrict__ h,
    const float* __restrict__ comb_l, const float* __restrict__ eps_p,
    unsigned short* __restrict__ zbuf)
{
    int n = blockIdx.x * 4 + (threadIdx.x >> 6);
    if (n >= N_NODES) return;
    int lane = threadIdx.x & 63;
    int sub = lane >> 3;          // edge slot 0..7
    int fo = (lane & 7) << 3;     // 8 features per lane

    int beg = off[n];
    int end = beg + cnt[n];

    const f32x2 zero2 = {0.f, 0.f};
    f32x2 a0 = zero2, a1 = zero2, a2 = zero2, a3 = zero2;

#define EDGE_ACC(PK)                                                               \
    {                                                                              \
        int pk_ = (PK);                                                            \
        uint4 hv = *reinterpret_cast<const uint4*>(h + (pk_ & 0x1FFFF) * HID + fo);\
        const float4* ep_ = reinterpret_cast<const float4*>(comb_l + (pk_ >> 17) * HID + fo); \
        float4 e0_ = ep_[0], e1_ = ep_[1];                                         \
        a0 += __builtin_elementwise_max(bfpair(hv.x) + (f32x2){e0_.x, e0_.y}, zero2); \
        a1 += __builtin_elementwise_max(bfpair(hv.y) + (f32x2){e0_.z, e0_.w}, zero2); \
        a2 += __builtin_elementwise_max(bfpair(hv.z) + (f32x2){e1_.x, e1_.y}, zero2); \
        a3 += __builtin_elementwise_max(bfpair(hv.w) + (f32x2){e1_.z, e1_.w}, zero2); \
    }

    int i = beg + sub;
    for (; i + 8 < end; i += 16) {
        int pk0 = csr_e[i];
        int pk1 = csr_e[i + 8];
        EDGE_ACC(pk0);
        EDGE_ACC(pk1);
    }
    if (i < end) EDGE_ACC(csr_e[i]);
#undef EDGE_ACC

    // reduce across the 8 sub-groups (lane bits 3,4,5)
    float r[8] = {a0.x, a0.y, a1.x, a1.y, a2.x, a2.y, a3.x, a3.y};
#pragma unroll
    for (int j = 0; j < 8; ++j) {
        r[j] += __shfl_xor(r[j], 8, 64);
        r[j] += __shfl_xor(r[j], 16, 64);
        r[j] += __shfl_xor(r[j], 32, 64);
    }

    if (sub == 0) {
        uint4 hn = *reinterpret_cast<const uint4*>(h + n * HID + fo);
        float ep1 = 1.0f + eps_p[0];
        f32x2 ep2 = {ep1, ep1};
        f32x2 z0 = __builtin_elementwise_max(ep2 * bfpair(hn.x) + (f32x2){r[0], r[1]}, zero2);
        f32x2 z1 = __builtin_elementwise_max(ep2 * bfpair(hn.y) + (f32x2){r[2], r[3]}, zero2);
        f32x2 z2 = __builtin_elementwise_max(ep2 * bfpair(hn.z) + (f32x2){r[4], r[5]}, zero2);
        f32x2 z3 = __builtin_elementwise_max(ep2 * bfpair(hn.w) + (f32x2){r[6], r[7]}, zero2);
        uint4 o;
        o.x = pack2bf(z0.x, z0.y);
        o.y = pack2bf(z1.x, z1.y);
        o.z = pack2bf(z2.x, z2.y);
        o.w = pack2bf(z3.x, z3.y);
        *reinterpret_cast<uint4*>(zbuf + n * HID + fo) = o;
    }
}

// ---------------------------------------------------------------------------
// MFMA node MLP. lin1 SWAPPED (A=w1, B=z -> D[o][node]): lane holds 4
// consecutive o per node -> u-tile stored as packed ds_write_b64 (XOR swizzle,
// conflict-free). lin2 unchanged (A=u node rows, B=w2 -> D[node][o2]) with
// run-merged pooling epilogue.
// ---------------------------------------------------------------------------
__global__ __launch_bounds__(256) void mlp_kernel(
    const unsigned short* __restrict__ zbuf, unsigned short* __restrict__ h,
    const unsigned short* __restrict__ w1b, const unsigned short* __restrict__ w2b,
    const float* __restrict__ alpha, const float* __restrict__ beta,
    const float* __restrict__ b2, const int* __restrict__ batch,
    float* __restrict__ out, int out_col, int write_h)
{
    __shared__ unsigned short us[64 * MLP_HID];   // 16 KB, node-major [node][128]
    __shared__ int sbatch[64];

    const int tid = threadIdx.x;
    const int lane = tid & 63;
    const int w = __builtin_amdgcn_readfirstlane(tid >> 6);
    const int base = blockIdx.x * 64;
    const int r16 = lane & 15;
    const int g4 = lane >> 4;                     // 0..3

    if (tid < 64) sbatch[tid] = (base + tid < N_NODES) ? batch[base + tid] : -1;

    // ---------------- lin1 (swapped): wave w owns o-tiles {2w, 2w+1}
    f32x4 acc[2][4];        // [o-tile][node-tile]
#pragma unroll
    for (int mo = 0; mo < 2; ++mo)
#pragma unroll
        for (int nt = 0; nt < 4; ++nt) acc[mo][nt] = (f32x4){0.f, 0.f, 0.f, 0.f};

    bf16x8 awf[2][2];       // A = w1 rows: o = (2w+mo)*16 + r16, k = kt*32 + g4*8
#pragma unroll
    for (int mo = 0; mo < 2; ++mo)
#pragma unroll
        for (int kt = 0; kt < 2; ++kt) {
            int o = (2 * w + mo) * 16 + r16;
            awf[mo][kt] = *reinterpret_cast<const bf16x8*>(w1b + o * HID + kt * 32 + g4 * 8);
        }

#pragma unroll
    for (int nt = 0; nt < 4; ++nt) {
        bf16x8 zf[2];       // B = z cols: node = nt*16 + r16, k = kt*32 + g4*8
#pragma unroll
        for (int kt = 0; kt < 2; ++kt)
            zf[kt] = *reinterpret_cast<const bf16x8*>(
                zbuf + (size_t)(base + nt * 16 + r16) * HID + kt * 32 + g4 * 8);
#pragma unroll
        for (int mo = 0; mo < 2; ++mo)
#pragma unroll
            for (int kt = 0; kt < 2; ++kt)
                acc[mo][nt] = __builtin_amdgcn_mfma_f32_16x16x32_bf16(
                    awf[mo][kt], zf[kt], acc[mo][nt], 0, 0, 0);
    }

    // BN-fold + relu -> us[node][o], packed b64 writes (4 consecutive o/lane)
    char* usb = (char*)us;
#pragma unroll
    for (int mo = 0; mo < 2; ++mo) {
        int o0 = (2 * w + mo) * 16 + g4 * 4;
        float4 al = *reinterpret_cast<const float4*>(alpha + o0);
        float4 be = *reinterpret_cast<const float4*>(beta + o0);
#pragma unroll
        for (int nt = 0; nt < 4; ++nt) {
            int node = nt * 16 + r16;
            f32x4 a = acc[mo][nt];
            unsigned lo = pack2bf(fmaxf(a[0] * al.x + be.x, 0.f),
                                  fmaxf(a[1] * al.y + be.y, 0.f));
            unsigned hi = pack2bf(fmaxf(a[2] * al.z + be.z, 0.f),
                                  fmaxf(a[3] * al.w + be.w, 0.f));
            int byte = (node * 256 + o0 * 2) ^ ((node & 7) << 4);
            *reinterpret_cast<uint2*>(usb + byte) = make_uint2(lo, hi);
        }
    }
    __syncthreads();

    // ---------------- lin2: A = u (node rows), B = w2 -> D[node][o2]
    f32x4 acc2[4];
#pragma unroll
    for (int mt = 0; mt < 4; ++mt) acc2[mt] = (f32x4){0.f, 0.f, 0.f, 0.f};

    bf16x8 b2frag[4];
#pragma unroll
    for (int kt = 0; kt < 4; ++kt)
        b2frag[kt] = *reinterpret_cast<const bf16x8*>(
            w2b + (w * 16 + r16) * MLP_HID + kt * 32 + g4 * 8);

#pragma unroll
    for (int mt = 0; mt < 4; ++mt) {
#pragma unroll
        for (int kt = 0; kt < 4; ++kt) {
            int node = mt * 16 + r16;
            int byte = (node * 256 + (kt * 32 + g4 * 8) * 2) ^ ((node & 7) << 4);
            bf16x8 af = *reinterpret_cast<const bf16x8*>(usb + byte);
            acc2[mt] = __builtin_amdgcn_mfma_f32_16x16x32_bf16(
                af, b2frag[kt], acc2[mt], 0, 0, 0);
        }
    }

    // ---------------- epilogue: relu(acc2 + b2), h store, run-merged pooling
    {
        int o = w * 16 + r16;
        float bias = b2[o];
        int gprev = -2;
        float run = 0.f;
#pragma unroll
        for (int mt = 0; mt < 4; ++mt) {
#pragma unroll
            for (int r = 0; r < 4; ++r) {
                int node = mt * 16 + g4 * 4 + r;
                int gn = base + node;
                float v = fmaxf(acc2[mt][r] + bias, 0.f);
                if (write_h && gn < N_NODES) h[(size_t)gn * HID + o] = f2bf(v);
                int gb = sbatch[node];
                if (gb != gprev) {
                    if (gprev >= 0) atomicAdd(&out[gprev * 256 + out_col + o], run);
                    run = 0.f;
                    gprev = gb;
                }
                if (gb >= 0) run += v;
            }
        }
        if (gprev >= 0) atomicAdd(&out[gprev * 256 + out_col + o], run);
    }
}

// ---------------------------------------------------------------------------
extern "C" void kernel_launch(void* const* d_in, const int* in_sizes, int n_in,
                              void* d_out, int out_size, void* d_ws, size_t ws_size,
                              hipStream_t stream)
{
    const int*   x        = (const int*)d_in[0];
    const int*   ei       = (const int*)d_in[1];
    const int*   ea       = (const int*)d_in[2];
    const int*   batch    = (const int*)d_in[3];
    const float* atom_emb = (const float*)d_in[4];
    const float* edge_emb = (const float*)d_in[5];
    const float* w1       = (const float*)d_in[6];
    const float* b1       = (const float*)d_in[7];
    const float* bn_g     = (const float*)d_in[8];
    const float* bn_b     = (const float*)d_in[9];
    const float* bn_m     = (const float*)d_in[10];
    const float* bn_v     = (const float*)d_in[11];
    const float* w2       = (const float*)d_in[12];
    const float* b2       = (const float*)d_in[13];
    const float* eps      = (const float*)d_in[14];

    float* out = (float*)d_out;

    // workspace layout (all chunks 16B-aligned)
    const size_t NODE_PAD = 100064;
    char* ws = (char*)d_ws;
    unsigned short* h     = (unsigned short*)ws; ws += NODE_PAD * HID * 2;            // 12.8 MB
    unsigned short* zbuf  = (unsigned short*)ws; ws += NODE_PAD * HID * 2;            // 12.8 MB
    float* comb           = (float*)ws;          ws += (size_t)3 * N_COMBO * HID * 4; // 203 KB
    unsigned short* w1b   = (unsigned short*)ws; ws += (size_t)3 * MLP_HID * HID * 2;
    unsigned short* w2b   = (unsigned short*)ws; ws += (size_t)3 * HID * MLP_HID * 2;
    float* alpha          = (float*)ws;          ws += (size_t)3 * MLP_HID * 4;
    float* betab          = (float*)ws;          ws += (size_t)3 * MLP_HID * 4;
    int*   cnt            = (int*)ws;            ws += (size_t)N_NODES * 4;
    int*   off            = (int*)ws;            ws += (size_t)N_NODES * 4;
    int*   bcnt           = (int*)ws;            ws += 128 * 4;
    int*   bbase          = (int*)ws;            ws += 128 * 4;
    int*   bcur           = (int*)ws;            ws += 128 * 4;
    uint2* ebuf           = (uint2*)ws;          ws += (size_t)N_EDGES * 8;           // 12.8 MB
    int*   csr_e          = (int*)ws;            ws += (size_t)N_EDGES * 4;           // 6.4 MB

    const int nblk64 = (N_NODES + 63) / 64;      // 1563
    const int NPREP = 3 * N_COMBO * HID + 3 * MLP_HID * HID + 3 * MLP_HID;

    hipMemsetAsync(out, 0, (size_t)N_GRAPHS * 256 * sizeof(float), stream);
    hipMemsetAsync(bcnt, 0, 128 * sizeof(int), stream);

    atom_embed_kernel<<<(N_NODES * 16 + 255) / 256, 256, 0, stream>>>(x, atom_emb, h);

    bhist_kernel<<<(N_EDGES + 4095) / 4096, 256, 0, stream>>>(ei, bcnt);
    bscan_kernel<<<1, 64, 0, stream>>>(bcnt, bbase, bcur);
    bscatter_kernel<<<(N_EDGES + CHUNK - 1) / CHUNK, 256, 0, stream>>>(ei, ea, bcur, ebuf);
    csr_build_kernel<<<NBUCK, 256, 0, stream>>>(ebuf, bbase, cnt, off, csr_e);

    prep_kernel<<<(NPREP + 255) / 256, 256, 0, stream>>>(
        edge_emb, w1, w2, b1, bn_g, bn_b, bn_m, bn_v, comb, w1b, w2b, alpha, betab);

    pool_kernel<<<nblk64, 256, 0, stream>>>(h, batch, out, 0);

    for (int l = 0; l < 3; ++l) {
        gather_kernel<<<(N_NODES + 3) / 4, 256, 0, stream>>>(
            cnt, off, csr_e, h, comb + (size_t)l * N_COMBO * HID, eps + l, zbuf);
        mlp_kernel<<<nblk64, 256, 0, stream>>>(
            zbuf, h,
            w1b + (size_t)l * MLP_HID * HID, w2b + (size_t)l * HID * MLP_HID,
            alpha + (size_t)l * MLP_HID, betab + (size_t)l * MLP_HID,
            b2 + (size_t)l * HID, batch, out, (l + 1) * HID, (l < 2) ? 1 : 0);
    }
}

// Round 8
// 308.593 us; speedup vs baseline: 14.9921x; 1.0990x over previous
//
#include <hip/hip_runtime.h>

#define N_NODES 100000
#define N_EDGES 1600000
#define N_GRAPHS 1024
#define HID 64
#define MLP_HID 128
#define N_COMBO 264    // 22*6*2 edge-attr combinations
#define NBUCK 98       // ceil(N_NODES / 1024)
#define CHUNK 6144     // edges per bscatter block (48KB LDS staging)

#define NB_EMBED 1563  // (N_NODES+63)/64
#define NPREP (3*N_COMBO*HID + 3*MLP_HID*HID + 3*MLP_HID)   // 75648
#define NB_PREP 296    // ceil(NPREP/256)
#define NB_HIST 391    // (N_EDGES+4095)/4096

typedef __attribute__((ext_vector_type(8))) short bf16x8;
typedef __attribute__((ext_vector_type(4))) float f32x4;
typedef __attribute__((ext_vector_type(2))) float f32x2;

static __device__ __forceinline__ float bf2f(unsigned short u) {
    union { unsigned int i; float f; } v; v.i = ((unsigned int)u) << 16; return v.f;
}
static __device__ __forceinline__ unsigned short f2bf(float f) {
    union { float f; unsigned int i; } v; v.f = f;
    unsigned int u = v.i;
    unsigned int r = u + 0x7FFFu + ((u >> 16) & 1u);   // RNE
    return (unsigned short)(r >> 16);
}
static __device__ __forceinline__ f32x2 bfpair(unsigned int u) {
    union { unsigned int i; float f; } lo, hi;
    lo.i = u << 16;
    hi.i = u & 0xFFFF0000u;
    f32x2 r; r.x = lo.f; r.y = hi.f; return r;
}
static __device__ __forceinline__ unsigned int pack2bf(float a, float b) {
    return (unsigned int)f2bf(a) | ((unsigned int)f2bf(b) << 16);
}

// ---------------------------------------------------------------------------
// Fused misc kernel: [0,NB_EMBED) atom-embed + pooled[0];
//                    [NB_EMBED, +NB_PREP) weight/comb prep;
//                    [.., +NB_HIST) bucket histogram.
// ---------------------------------------------------------------------------
__global__ __launch_bounds__(256) void misc_kernel(
    const int* __restrict__ x, const float* __restrict__ atom_emb,
    const int* __restrict__ batch, unsigned short* __restrict__ h,
    float* __restrict__ out,
    const float* __restrict__ edge_emb,
    const float* __restrict__ w1, const float* __restrict__ w2,
    const float* __restrict__ b1, const float* __restrict__ bn_g,
    const float* __restrict__ bn_b, const float* __restrict__ bn_m,
    const float* __restrict__ bn_v,
    float* __restrict__ comb,
    unsigned short* __restrict__ w1b, unsigned short* __restrict__ w2b,
    float* __restrict__ alpha, float* __restrict__ beta,
    const int* __restrict__ ei, int* __restrict__ bcnt)
{
    __shared__ int s_hist[NBUCK];
    const int bid = blockIdx.x;
    const int tid = threadIdx.x;

    if (bid < NB_EMBED) {
        // ---- atom embedding (9-table sum) + pooled[0], (f, quarter) layout
        int f = tid & 63;
        int q = __builtin_amdgcn_readfirstlane(tid >> 6);   // wave-uniform
        int base = bid * 64 + q * 16;
        float run = 0.f;
        int cg = -1;
        for (int k = 0; k < 16; ++k) {
            int gn = base + k;
            if (gn >= N_NODES) break;
            const int* xp = x + gn * 9;                     // uniform -> s_load
            float acc = 0.f;
#pragma unroll
            for (int j = 0; j < 9; ++j) {
                int idx = xp[j];
                acc += atom_emb[(j * 119 + idx) * HID + f]; // coalesced 256B
            }
            h[(size_t)gn * HID + f] = f2bf(acc);
            int g = batch[gn];                              // uniform
            if (g != cg) {
                if (cg >= 0) atomicAdd(&out[cg * 256 + f], run);
                run = 0.f; cg = g;
            }
            run += acc;
        }
        if (cg >= 0) atomicAdd(&out[cg * 256 + f], run);
    } else if (bid < NB_EMBED + NB_PREP) {
        // ---- prep: f32 comb table, bf16 weights, folded BN affine
        int t = (bid - NB_EMBED) * 256 + tid;
        const int NC = 3 * N_COMBO * HID;   // 50688
        const int NW = 3 * MLP_HID * HID;   // 24576
        if (t < NC) {
            int d = t & 63;
            int c = (t >> 6) % N_COMBO;
            int l = (t >> 6) / N_COMBO;
            int a0 = c / 12, r = c % 12, a1 = r >> 1, a2 = r & 1;
            const float* base = edge_emb + (size_t)l * 3 * 22 * HID;
            comb[t] = base[(0 * 22 + a0) * HID + d]
                    + base[(1 * 22 + a1) * HID + d]
                    + base[(2 * 22 + a2) * HID + d];
        } else if (t < NC + NW) {
            int i = t - NC;
            w1b[i] = f2bf(w1[i]);
            w2b[i] = f2bf(w2[i]);
        } else if (t < NC + NW + 3 * MLP_HID) {
            int i = t - NC - NW;
            float a = rsqrtf(bn_v[i] + 1e-5f) * bn_g[i];
            alpha[i] = a;
            beta[i] = (b1[i] - bn_m[i]) * a + bn_b[i];
        }
    } else {
        // ---- bucket histogram
        int b = bid - NB_EMBED - NB_PREP;
        for (int i = tid; i < NBUCK; i += 256) s_hist[i] = 0;
        __syncthreads();
        int base = b * 4096;
        int n_here = min(4096, N_EDGES - base);
        for (int i = tid; i < n_here; i += 256)
            atomicAdd(&s_hist[ei[N_EDGES + base + i] >> 10], 1);
        __syncthreads();
        for (int i = tid; i < NBUCK; i += 256)
            if (s_hist[i]) atomicAdd(&bcnt[i], s_hist[i]);
    }
}

// ---------------------------------------------------------------------------
// bscan: parallel exclusive scan of bcnt (Hillis-Steele over 128 lanes)
// ---------------------------------------------------------------------------
__global__ __launch_bounds__(128) void bscan_kernel(
    const int* __restrict__ bcnt, int* __restrict__ bbase, int* __restrict__ bcur)
{
    __shared__ int buf[128];
    int t = threadIdx.x;
    int v = (t < NBUCK) ? bcnt[t] : 0;
    buf[t] = v;
    __syncthreads();
    for (int s = 1; s < 128; s <<= 1) {
        int u = (t >= s) ? buf[t - s] : 0;
        __syncthreads();
        buf[t] += u;
        __syncthreads();
    }
    int excl = buf[t] - v;     // exclusive prefix
    if (t < NBUCK) { bbase[t] = excl; bcur[t] = excl; }
    if (t == NBUCK) bbase[NBUCK] = excl;   // = total (v=0 beyond NBUCK)
}

// ---------------------------------------------------------------------------
// bscatter: LDS-staged reorder by bucket, then coalesced run copy-out.
// ---------------------------------------------------------------------------
__global__ __launch_bounds__(256) void bscatter_kernel(
    const int* __restrict__ ei, const int* __restrict__ ea,
    int* __restrict__ bcur, uint2* __restrict__ ebuf)
{
    __shared__ uint2 stage[CHUNK];      // 48 KB
    __shared__ int hist[NBUCK];
    __shared__ int lbase[NBUCK];
    __shared__ int shift[NBUCK];

    int tid = threadIdx.x;
    int base = blockIdx.x * CHUNK;
    int n_here = min(CHUNK, N_EDGES - base);

    for (int i = tid; i < NBUCK; i += 256) hist[i] = 0;
    __syncthreads();
    for (int i = tid; i < n_here; i += 256)
        atomicAdd(&hist[ei[N_EDGES + base + i] >> 10], 1);
    __syncthreads();
    if (tid == 0) {
        int run = 0;
        for (int b = 0; b < NBUCK; ++b) { lbase[b] = run; run += hist[b]; }
    }
    __syncthreads();
    if (tid < NBUCK) {
        int c = hist[tid];
        if (c > 0) {
            int g = atomicAdd(&bcur[tid], c);
            shift[tid] = g - lbase[tid];
        }
        hist[tid] = lbase[tid];
    }
    __syncthreads();
    for (int i = tid; i < n_here; i += 256) {
        int e = base + i;
        int src = ei[e];
        int dst = ei[N_EDGES + e];
        int combo = (ea[e * 3 + 0] * 6 + ea[e * 3 + 1]) * 2 + ea[e * 3 + 2];
        int pos = atomicAdd(&hist[dst >> 10], 1);
        stage[pos] = make_uint2((unsigned)(src | (combo << 17)), (unsigned)dst);
    }
    __syncthreads();
    for (int i = tid; i < n_here; i += 256) {
        uint2 en = stage[i];
        ebuf[shift[en.y >> 10] + i] = en;
    }
}

__global__ __launch_bounds__(256) void csr_build_kernel(
    const uint2* __restrict__ ebuf, const int* __restrict__ bbase,
    int* __restrict__ cnt, int* __restrict__ off, int* __restrict__ csr_e)
{
    __shared__ int nh[1024];
    __shared__ int cur[1024];
    __shared__ int part[256];

    int b = blockIdx.x;
    int tid = threadIdx.x;
    int nodeBase = b << 10;
    int limit = min(1024, N_NODES - nodeBase);
    int beg = bbase[b], end = bbase[b + 1];

    for (int i = tid; i < 1024; i += 256) nh[i] = 0;
    __syncthreads();
    for (int i = beg + tid; i < end; i += 256)
        atomicAdd(&nh[ebuf[i].y - nodeBase], 1);
    __syncthreads();

    int s0 = nh[tid * 4], s1 = nh[tid * 4 + 1], s2 = nh[tid * 4 + 2], s3 = nh[tid * 4 + 3];
    part[tid] = s0 + s1 + s2 + s3;
    __syncthreads();
    for (int st = 1; st < 256; st <<= 1) {
        int v = 0;
        if (tid >= st) v = part[tid - st];
        __syncthreads();
        if (tid >= st) part[tid] += v;
        __syncthreads();
    }
    int e0 = (tid ? part[tid - 1] : 0);
    int e1 = e0 + s0, e2 = e1 + s1, e3 = e2 + s2;
    cur[tid * 4 + 0] = e0; cur[tid * 4 + 1] = e1;
    cur[tid * 4 + 2] = e2; cur[tid * 4 + 3] = e3;
    int excl[4] = {e0, e1, e2, e3};
    int cval[4] = {s0, s1, s2, s3};
#pragma unroll
    for (int j = 0; j < 4; ++j) {
        int nl = tid * 4 + j;
        if (nl < limit) {
            cnt[nodeBase + nl] = cval[j];
            off[nodeBase + nl] = beg + excl[j];
        }
    }
    __syncthreads();
    for (int i = beg + tid; i < end; i += 256) {
        uint2 en = ebuf[i];
        int pos = atomicAdd(&cur[en.y - nodeBase], 1);
        csr_e[beg + pos] = (int)en.x;
    }
}

// ---------------------------------------------------------------------------
// Gather (unchanged): wave per node; 8 x 8-lane groups; lane = 8 features.
// ---------------------------------------------------------------------------
__global__ __launch_bounds__(256) void gather_kernel(
    const int* __restrict__ cnt, const int* __restrict__ off,
    const int* __restrict__ csr_e, const unsigned short* __restrict__ h,
    const float* __restrict__ comb_l, const float* __restrict__ eps_p,
    unsigned short* __restrict__ zbuf)
{
    int n = blockIdx.x * 4 + (threadIdx.x >> 6);
    if (n >= N_NODES) return;
    int lane = threadIdx.x & 63;
    int sub = lane >> 3;          // edge slot 0..7
    int fo = (lane & 7) << 3;     // 8 features per lane

    int beg = off[n];
    int end = beg + cnt[n];

    const f32x2 zero2 = {0.f, 0.f};
    f32x2 a0 = zero2, a1 = zero2, a2 = zero2, a3 = zero2;

#define EDGE_ACC(PK)                                                               \
    {                                                                              \
        int pk_ = (PK);                                                            \
        uint4 hv = *reinterpret_cast<const uint4*>(h + (pk_ & 0x1FFFF) * HID + fo);\
        const float4* ep_ = reinterpret_cast<const float4*>(comb_l + (pk_ >> 17) * HID + fo); \
        float4 e0_ = ep_[0], e1_ = ep_[1];                                         \
        a0 += __builtin_elementwise_max(bfpair(hv.x) + (f32x2){e0_.x, e0_.y}, zero2); \
        a1 += __builtin_elementwise_max(bfpair(hv.y) + (f32x2){e0_.z, e0_.w}, zero2); \
        a2 += __builtin_elementwise_max(bfpair(hv.z) + (f32x2){e1_.x, e1_.y}, zero2); \
        a3 += __builtin_elementwise_max(bfpair(hv.w) + (f32x2){e1_.z, e1_.w}, zero2); \
    }

    int i = beg + sub;
    for (; i + 8 < end; i += 16) {
        int pk0 = csr_e[i];
        int pk1 = csr_e[i + 8];
        EDGE_ACC(pk0);
        EDGE_ACC(pk1);
    }
    if (i < end) EDGE_ACC(csr_e[i]);
#undef EDGE_ACC

    float r[8] = {a0.x, a0.y, a1.x, a1.y, a2.x, a2.y, a3.x, a3.y};
#pragma unroll
    for (int j = 0; j < 8; ++j) {
        r[j] += __shfl_xor(r[j], 8, 64);
        r[j] += __shfl_xor(r[j], 16, 64);
        r[j] += __shfl_xor(r[j], 32, 64);
    }

    if (sub == 0) {
        uint4 hn = *reinterpret_cast<const uint4*>(h + n * HID + fo);
        float ep1 = 1.0f + eps_p[0];
        f32x2 ep2 = {ep1, ep1};
        f32x2 z0 = __builtin_elementwise_max(ep2 * bfpair(hn.x) + (f32x2){r[0], r[1]}, zero2);
        f32x2 z1 = __builtin_elementwise_max(ep2 * bfpair(hn.y) + (f32x2){r[2], r[3]}, zero2);
        f32x2 z2 = __builtin_elementwise_max(ep2 * bfpair(hn.z) + (f32x2){r[4], r[5]}, zero2);
        f32x2 z3 = __builtin_elementwise_max(ep2 * bfpair(hn.w) + (f32x2){r[6], r[7]}, zero2);
        uint4 o;
        o.x = pack2bf(z0.x, z0.y);
        o.y = pack2bf(z1.x, z1.y);
        o.z = pack2bf(z2.x, z2.y);
        o.w = pack2bf(z3.x, z3.y);
        *reinterpret_cast<uint4*>(zbuf + n * HID + fo) = o;
    }
}

// ---------------------------------------------------------------------------
// MFMA node MLP, 128-node tiles. lin1 swapped (A=w1, B=z -> D[o][node]) with
// per-node-tile streaming epilogue into XOR-swizzled bf16 LDS; lin2
// (A=u rows, B=w2 -> D[node][o2]) with run-merged pooling epilogue.
// ---------------------------------------------------------------------------
__global__ __launch_bounds__(256) void mlp_kernel(
    const unsigned short* __restrict__ zbuf, unsigned short* __restrict__ h,
    const unsigned short* __restrict__ w1b, const unsigned short* __restrict__ w2b,
    const float* __restrict__ alpha, const float* __restrict__ beta,
    const float* __restrict__ b2, const int* __restrict__ batch,
    float* __restrict__ out, int out_col, int write_h)
{
    __shared__ unsigned short us[128 * MLP_HID];   // 32 KB
    __shared__ int sbatch[128];

    const int tid = threadIdx.x;
    const int lane = tid & 63;
    const int w = __builtin_amdgcn_readfirstlane(tid >> 6);
    const int base = blockIdx.x * 128;
    const int r16 = lane & 15;
    const int g4 = lane >> 4;                     // 0..3

    if (tid < 128) sbatch[tid] = (base + tid < N_NODES) ? batch[base + tid] : -1;

    // ---------------- lin1: wave w owns o-tiles {2w, 2w+1} (32 outputs)
    bf16x8 awf[2][2];
#pragma unroll
    for (int mo = 0; mo < 2; ++mo)
#pragma unroll
        for (int kt = 0; kt < 2; ++kt) {
            int o = (2 * w + mo) * 16 + r16;
            awf[mo][kt] = *reinterpret_cast<const bf16x8*>(w1b + o * HID + kt * 32 + g4 * 8);
        }
    float4 al[2], be[2];
#pragma unroll
    for (int mo = 0; mo < 2; ++mo) {
        int o0 = (2 * w + mo) * 16 + g4 * 4;
        al[mo] = *reinterpret_cast<const float4*>(alpha + o0);
        be[mo] = *reinterpret_cast<const float4*>(beta + o0);
    }

    char* usb = (char*)us;
#pragma unroll
    for (int nt = 0; nt < 8; ++nt) {
        bf16x8 zf[2];
#pragma unroll
        for (int kt = 0; kt < 2; ++kt)
            zf[kt] = *reinterpret_cast<const bf16x8*>(
                zbuf + (size_t)(base + nt * 16 + r16) * HID + kt * 32 + g4 * 8);
        f32x4 acc[2] = {(f32x4){0.f, 0.f, 0.f, 0.f}, (f32x4){0.f, 0.f, 0.f, 0.f}};
#pragma unroll
        for (int mo = 0; mo < 2; ++mo)
#pragma unroll
            for (int kt = 0; kt < 2; ++kt)
                acc[mo] = __builtin_amdgcn_mfma_f32_16x16x32_bf16(
                    awf[mo][kt], zf[kt], acc[mo], 0, 0, 0);
        int node = nt * 16 + r16;
#pragma unroll
        for (int mo = 0; mo < 2; ++mo) {
            int o0 = (2 * w + mo) * 16 + g4 * 4;
            f32x4 a = acc[mo];
            unsigned lo = pack2bf(fmaxf(a[0] * al[mo].x + be[mo].x, 0.f),
                                  fmaxf(a[1] * al[mo].y + be[mo].y, 0.f));
            unsigned hi = pack2bf(fmaxf(a[2] * al[mo].z + be[mo].z, 0.f),
                                  fmaxf(a[3] * al[mo].w + be[mo].w, 0.f));
            int byte = (node * 256 + o0 * 2) ^ ((node & 7) << 4);
            *reinterpret_cast<uint2*>(usb + byte) = make_uint2(lo, hi);
        }
    }
    __syncthreads();

    // ---------------- lin2: wave w owns o2 in [16w, 16w+16)
    bf16x8 b2frag[4];
#pragma unroll
    for (int kt = 0; kt < 4; ++kt)
        b2frag[kt] = *reinterpret_cast<const bf16x8*>(
            w2b + (w * 16 + r16) * MLP_HID + kt * 32 + g4 * 8);

    const int o = w * 16 + r16;
    const float bias = b2[o];
    int gprev = -2;
    float run = 0.f;
#pragma unroll
    for (int mt = 0; mt < 8; ++mt) {
        f32x4 acc2 = (f32x4){0.f, 0.f, 0.f, 0.f};
#pragma unroll
        for (int kt = 0; kt < 4; ++kt) {
            int node = mt * 16 + r16;
            int byte = (node * 256 + (kt * 32 + g4 * 8) * 2) ^ ((node & 7) << 4);
            bf16x8 af = *reinterpret_cast<const bf16x8*>(usb + byte);
            acc2 = __builtin_amdgcn_mfma_f32_16x16x32_bf16(af, b2frag[kt], acc2, 0, 0, 0);
        }
#pragma unroll
        for (int r = 0; r < 4; ++r) {
            int node = mt * 16 + g4 * 4 + r;
            int gn = base + node;
            float v = fmaxf(acc2[r] + bias, 0.f);
            if (write_h && gn < N_NODES) h[(size_t)gn * HID + o] = f2bf(v);
            int gb = sbatch[node];
            if (gb != gprev) {
                if (gprev >= 0) atomicAdd(&out[gprev * 256 + out_col + o], run);
                run = 0.f;
                gprev = gb;
            }
            if (gb >= 0) run += v;
        }
    }
    if (gprev >= 0) atomicAdd(&out[gprev * 256 + out_col + o], run);
}

// ---------------------------------------------------------------------------
extern "C" void kernel_launch(void* const* d_in, const int* in_sizes, int n_in,
                              void* d_out, int out_size, void* d_ws, size_t ws_size,
                              hipStream_t stream)
{
    const int*   x        = (const int*)d_in[0];
    const int*   ei       = (const int*)d_in[1];
    const int*   ea       = (const int*)d_in[2];
    const int*   batch    = (const int*)d_in[3];
    const float* atom_emb = (const float*)d_in[4];
    const float* edge_emb = (const float*)d_in[5];
    const float* w1       = (const float*)d_in[6];
    const float* b1       = (const float*)d_in[7];
    const float* bn_g     = (const float*)d_in[8];
    const float* bn_b     = (const float*)d_in[9];
    const float* bn_m     = (const float*)d_in[10];
    const float* bn_v     = (const float*)d_in[11];
    const float* w2       = (const float*)d_in[12];
    const float* b2       = (const float*)d_in[13];
    const float* eps      = (const float*)d_in[14];

    float* out = (float*)d_out;

    // workspace layout (all chunks 16B-aligned)
    const size_t NODE_PAD = 100096;   // 782*128 rows (mlp tail reads)
    char* ws = (char*)d_ws;
    unsigned short* h     = (unsigned short*)ws; ws += NODE_PAD * HID * 2;            // 12.8 MB
    unsigned short* zbuf  = (unsigned short*)ws; ws += NODE_PAD * HID * 2;            // 12.8 MB
    float* comb           = (float*)ws;          ws += (size_t)3 * N_COMBO * HID * 4; // 203 KB
    unsigned short* w1b   = (unsigned short*)ws; ws += (size_t)3 * MLP_HID * HID * 2;
    unsigned short* w2b   = (unsigned short*)ws; ws += (size_t)3 * HID * MLP_HID * 2;
    float* alpha          = (float*)ws;          ws += (size_t)3 * MLP_HID * 4;
    float* betab          = (float*)ws;          ws += (size_t)3 * MLP_HID * 4;
    int*   cnt            = (int*)ws;            ws += (size_t)N_NODES * 4;
    int*   off            = (int*)ws;            ws += (size_t)N_NODES * 4;
    int*   bcnt           = (int*)ws;            ws += 128 * 4;
    int*   bbase          = (int*)ws;            ws += 128 * 4;
    int*   bcur           = (int*)ws;            ws += 128 * 4;
    uint2* ebuf           = (uint2*)ws;          ws += (size_t)N_EDGES * 8;           // 12.8 MB
    int*   csr_e          = (int*)ws;            ws += (size_t)N_EDGES * 4;           // 6.4 MB

    const int nblk128 = (N_NODES + 127) / 128;   // 782

    hipMemsetAsync(out, 0, (size_t)N_GRAPHS * 256 * sizeof(float), stream);
    hipMemsetAsync(bcnt, 0, 128 * sizeof(int), stream);

    misc_kernel<<<NB_EMBED + NB_PREP + NB_HIST, 256, 0, stream>>>(
        x, atom_emb, batch, h, out,
        edge_emb, w1, w2, b1, bn_g, bn_b, bn_m, bn_v,
        comb, w1b, w2b, alpha, betab, ei, bcnt);

    bscan_kernel<<<1, 128, 0, stream>>>(bcnt, bbase, bcur);
    bscatter_kernel<<<(N_EDGES + CHUNK - 1) / CHUNK, 256, 0, stream>>>(ei, ea, bcur, ebuf);
    csr_build_kernel<<<NBUCK, 256, 0, stream>>>(ebuf, bbase, cnt, off, csr_e);

    for (int l = 0; l < 3; ++l) {
        gather_kernel<<<(N_NODES + 3) / 4, 256, 0, stream>>>(
            cnt, off, csr_e, h, comb + (size_t)l * N_COMBO * HID, eps + l, zbuf);
        mlp_kernel<<<nblk128, 256, 0, stream>>>(
            zbuf, h,
            w1b + (size_t)l * MLP_HID * HID, w2b + (size_t)l * HID * MLP_HID,
            alpha + (size_t)l * MLP_HID, betab + (size_t)l * MLP_HID,
            b2 + (size_t)l * HID, batch, out, (l + 1) * HID, (l < 2) ? 1 : 0);
    }
}